// Round 8
// baseline (1222.637 us; speedup 1.0000x reference)
//
#include <hip/hip_runtime.h>

typedef __attribute__((ext_vector_type(8))) short bf16x8;
typedef __attribute__((ext_vector_type(4))) float f32x4;
typedef __attribute__((ext_vector_type(4))) unsigned int u32x4;

constexpr int L_ = 4096, S_ = 4096, D_ = 2048, H_ = 16, HD_ = 128;
constexpr int LDSS = 72; // padded stride for the small kernels

__device__ __forceinline__ unsigned short f2bf(float f) {
    unsigned int u = __builtin_bit_cast(unsigned int, f);
    return (unsigned short)((u + 0x7fffu + ((u >> 16) & 1u)) >> 16);
}
__device__ __forceinline__ float bf2f(unsigned short h) {
    unsigned int u = ((unsigned int)h) << 16;
    return __builtin_bit_cast(float, u);
}
__device__ __forceinline__ unsigned long long pack4(float a, float b, float c, float d) {
    return (unsigned long long)f2bf(a) | ((unsigned long long)f2bf(b) << 16)
         | ((unsigned long long)f2bf(c) << 32) | ((unsigned long long)f2bf(d) << 48);
}
__device__ __forceinline__ float featmap(float x) {
    return x > 0.f ? x + 1.f : __expf(x);
}
__device__ __forceinline__ void gload16(const unsigned short* g, unsigned short* l) {
    __builtin_amdgcn_global_load_lds(
        (const __attribute__((address_space(1))) void*)g,
        (__attribute__((address_space(3))) void*)l, 16, 0, 0);
}

// fp32 -> bf16 bulk convert
__global__ __launch_bounds__(256) void cvt_bf16(
    const float* __restrict__ in, unsigned short* __restrict__ out, int n8)
{
    const int stride = gridDim.x * 256;
    for (int i = blockIdx.x * 256 + threadIdx.x; i < n8; i += stride) {
        const float4 a = ((const float4*)in)[2 * i];
        const float4 b = ((const float4*)in)[2 * i + 1];
        unsigned long long* o = (unsigned long long*)&out[(size_t)i * 8];
        o[0] = pack4(a.x, a.y, a.z, a.w);
        o[1] = pack4(b.x, b.y, b.z, b.w);
    }
}

// ============ 256x256 8-phase GEMM, one-phase-ahead register pipeline ============
// C = A @ B^T. BK=64, 2 K-tiles/body (buf0=even tile, buf1=odd). 8 waves, per-wave
// C=128x64. Phase p: {ds_reads for phase p+1} || {1 stage} || {16 MFMA on regs read
// in phase p-1}; then lgkmcnt(0); [vmcnt(4) at P1/P5]; s_barrier. Reads complete
// under the MFMA shadow; lgkm0-before-barrier closes the WAR window for staging.
// Quadrant order Q00,Q01,Q11,Q10 shares one operand between consecutive phases:
// 24 ds_read_b128/tile/wave (vs 32). A-slots fixed (avx=A0,avy=A1); B-slots
// alternate parity per tile (even: B0=bva,B1=bvb; odd: swapped) — statically
// unrolled. vmcnt(4) at P1 retires tile(2i+1)'s 8 stages; at P5 retires tile(2i+2).
template<int MODE, int NBN>
__global__ __launch_bounds__(512, 2) void gemm256(
    const unsigned short* __restrict__ A, const unsigned short* __restrict__ B,
    unsigned short* __restrict__ C1, unsigned short* __restrict__ C2,
    float* __restrict__ Cf, const float* __restrict__ bias)
{
    __shared__ alignas(16) unsigned short lds[65536];   // 128 KiB
    const int tid = threadIdx.x;
    const int lane = tid & 63, w = tid >> 6;
    const int wr = w >> 2, wc = w & 3;
    const int lr = lane & 15;
    const int lk8 = (lane >> 4) * 8;          // K-element offset within 32-group
    const int rsw = (lr & 7) << 3;            // read-side swizzle (shorts)
    const int lsub = lane >> 3;               // 0..7
    const int scol = ((lane & 7) ^ lsub) * 8; // pre-swizzled source col (elements)

    // bijective XCD swizzle (nwg % 8 == 0 for all our grids)
    const int nwg = gridDim.x;
    const int wg = blockIdx.x;
    const int swz = (wg & 7) * (nwg >> 3) + (wg >> 3);
    const int bm = swz / NBN, bn = swz % NBN;
    const int row0 = bm * 256, bcol = bn * 256;

    const unsigned short* Ap = A + (size_t)row0 * D_;
    const unsigned short* Bp = B + (size_t)bcol * D_;
    const int rA = w * 8 + lsub;                              // A stage row (r=0)
    const int rB = ((w * 8 + lsub) >> 5) * 64 + ((w * 8 + lsub) & 31); // B stage row base

    f32x4 acc[8][4] = {};
    bf16x8 avx[2][4], avy[2][4];   // A0 / A1 fragment sets ([ks][mi])
    bf16x8 bva[2][2], bvb[2][2];   // B slot a / slot b ([ks][j])

#define STA(BUF, HH, KT) do { \
    const unsigned short* g_ = Ap + (size_t)((HH) * 64 + rA) * D_ + (KT) * 64 + scol; \
    unsigned short* l_ = &lds[(BUF) * 16384 + (HH) * 8192 + w * 512]; \
    gload16(g_, l_); gload16(g_ + (size_t)128 * D_, l_ + 4096); } while (0)

#define STB(BUF, HH, KT) do { \
    const unsigned short* g_ = Bp + (size_t)(rB + (HH) * 32) * D_ + (KT) * 64 + scol; \
    unsigned short* l_ = &lds[32768 + (BUF) * 16384 + (HH) * 8192 + w * 512]; \
    gload16(g_, l_); gload16(g_ + (size_t)128 * D_, l_ + 4096); } while (0)

#define RD_As(DST, MQ, BUF) \
    _Pragma("unroll") for (int mi = 0; mi < 4; mi++) \
    _Pragma("unroll") for (int ks = 0; ks < 2; ks++) \
        DST[ks][mi] = *(const bf16x8*)&lds[(BUF) * 16384 + (MQ) * 8192 \
            + (mi * 16 + lr + wr * 64) * 64 + ((ks * 32 + lk8) ^ rsw)];

#define RD_Bs(DST, NQ, BUF) \
    _Pragma("unroll") for (int j = 0; j < 2; j++) \
    _Pragma("unroll") for (int ks = 0; ks < 2; ks++) \
        DST[ks][j] = *(const bf16x8*)&lds[32768 + (BUF) * 16384 + (NQ) * 8192 \
            + (j * 16 + lr + wc * 32) * 64 + ((ks * 32 + lk8) ^ rsw)];

#define MFMA_G(MQ, NQ, AV, BV) \
    _Pragma("unroll") for (int mi = 0; mi < 4; mi++) \
    _Pragma("unroll") for (int j = 0; j < 2; j++) \
    _Pragma("unroll") for (int ks = 0; ks < 2; ks++) \
        acc[(MQ) * 4 + mi][(NQ) * 2 + j] = __builtin_amdgcn_mfma_f32_16x16x32_bf16( \
            AV[ks][mi], BV[ks][j], acc[(MQ) * 4 + mi][(NQ) * 2 + j], 0, 0, 0);

#define PRIO1 __builtin_amdgcn_s_setprio(1)
#define PRIO0 __builtin_amdgcn_s_setprio(0)
#define BAR __builtin_amdgcn_s_barrier()
#define LG0 asm volatile("s_waitcnt lgkmcnt(0)" ::: "memory")
#define VM4 asm volatile("s_waitcnt vmcnt(4)" ::: "memory")
#define VM0 asm volatile("s_waitcnt vmcnt(0)" ::: "memory")

    // ---- prologue: stage tiles 0 (buf0) and 1 (buf1); preload avx(A0,t0), bva(B0,t0)
    STA(0, 0, 0); STB(0, 0, 0); STA(0, 1, 0); STB(0, 1, 0);
    STA(1, 0, 1); STB(1, 0, 1); STA(1, 1, 1); STB(1, 1, 1);
    VM0; BAR;
    RD_As(avx, 0, 0);
    RD_Bs(bva, 0, 0);
    LG0;

    constexpr int NT = D_ / 64;       // 32 K-tiles
    for (int i = 0; i < NT / 2 - 1; i++) {
        const int t2 = 2 * i + 2, t3 = 2 * i + 3;
        // P0: Q00(even) on [avx,bva]; read B1(even)->bvb; stage A0(t2)
        RD_Bs(bvb, 1, 0); STA(0, 0, t2);
        PRIO1; MFMA_G(0, 0, avx, bva); PRIO0; LG0; BAR;
        // P1: Q01(even) on [avx,bvb]; read A1(even)->avy; stage B0(t2); gate tile 2i+1
        RD_As(avy, 1, 0); STB(0, 0, t2);
        PRIO1; MFMA_G(0, 1, avx, bvb); PRIO0; LG0; VM4; BAR;
        // P2: Q11(even) on [avy,bvb]; read A0(odd)->avx; stage A1(t2)
        RD_As(avx, 0, 1); STA(0, 1, t2);
        PRIO1; MFMA_G(1, 1, avy, bvb); PRIO0; LG0; BAR;
        // P3: Q10(even) on [avy,bva]; read B0(odd)->bvb; stage B1(t2)
        RD_Bs(bvb, 0, 1); STB(0, 1, t2);
        PRIO1; MFMA_G(1, 0, avy, bva); PRIO0; LG0; BAR;
        // P4: Q00(odd) on [avx,bvb]; read B1(odd)->bva; stage A0(t3)
        RD_Bs(bva, 1, 1); STA(1, 0, t3);
        PRIO1; MFMA_G(0, 0, avx, bvb); PRIO0; LG0; BAR;
        // P5: Q01(odd) on [avx,bva]; read A1(odd)->avy; stage B0(t3); gate tile 2i+2
        RD_As(avy, 1, 1); STB(1, 0, t3);
        PRIO1; MFMA_G(0, 1, avx, bva); PRIO0; LG0; VM4; BAR;
        // P6: Q11(odd) on [avy,bva]; read A0(t2)->avx; stage A1(t3)
        RD_As(avx, 0, 0); STA(1, 1, t3);
        PRIO1; MFMA_G(1, 1, avy, bva); PRIO0; LG0; BAR;
        // P7: Q10(odd) on [avy,bvb]; read B0(t2)->bva; stage B1(t3)
        RD_Bs(bva, 0, 0); STB(1, 1, t3);
        PRIO1; MFMA_G(1, 0, avy, bvb); PRIO0; LG0; BAR;
    }
    // ---- peeled final body (tiles NT-2 buf0, NT-1 buf1): no stages ----
    {
        RD_Bs(bvb, 1, 0);
        PRIO1; MFMA_G(0, 0, avx, bva); PRIO0; LG0; BAR;
        RD_As(avy, 1, 0);
        PRIO1; MFMA_G(0, 1, avx, bvb); PRIO0; LG0; VM0; BAR;
        RD_As(avx, 0, 1);
        PRIO1; MFMA_G(1, 1, avy, bvb); PRIO0; LG0; BAR;
        RD_Bs(bvb, 0, 1);
        PRIO1; MFMA_G(1, 0, avy, bva); PRIO0; LG0; BAR;
        RD_Bs(bva, 1, 1);
        PRIO1; MFMA_G(0, 0, avx, bvb); PRIO0; LG0; BAR;
        RD_As(avy, 1, 1);
        PRIO1; MFMA_G(0, 1, avx, bva); PRIO0; LG0; BAR;
        PRIO1; MFMA_G(1, 1, avy, bva); PRIO0; BAR;
        PRIO1; MFMA_G(1, 0, avy, bvb); PRIO0; BAR;
    }

    // ================= epilogue =================
    const int rb = (lane >> 4) * 4;
    const bool second = bn >= (NBN / 2);
    if (MODE == 1) {
        // transpose each 128(s) x 128(d) quadrant via LDS, store [bh][d][s]
        unsigned short* TT = lds;             // 128*136 shorts
        const int b = row0 >> 12;
        #pragma unroll
        for (int qd = 0; qd < 4; qd++) {
            const int sq = qd >> 1, dh = qd & 1;
            __syncthreads();
            if (wr == sq && (wc >> 1) == dh) {
                #pragma unroll
                for (int m = 0; m < 8; m++) {
                    #pragma unroll
                    for (int n = 0; n < 4; n++) {
                        float x0 = acc[m][n][0], x1 = acc[m][n][1];
                        float x2 = acc[m][n][2], x3 = acc[m][n][3];
                        if (!second) {
                            x0 = featmap(x0); x1 = featmap(x1);
                            x2 = featmap(x2); x3 = featmap(x3);
                        }
                        const int dcol = (wc & 1) * 64 + n * 16 + lr;
                        *(unsigned long long*)&TT[dcol * 136 + m * 16 + rb]
                            = pack4(x0, x1, x2, x3);
                    }
                }
            }
            __syncthreads();
            const int h2 = (bn & 7) * 2 + dh;
            const int s0 = (row0 + sq * 128) & (S_ - 1);
            unsigned short* dst = (second ? C2 : C1) + (size_t)(b * H_ + h2) * HD_ * S_;
            #pragma unroll
            for (int it = 0; it < 4; it++) {
                const int idx = it * 512 + tid;
                const int d = idx >> 4, sc2 = (idx & 15) * 8;
                *(u32x4*)&dst[(size_t)d * S_ + s0 + sc2] = *(const u32x4*)&TT[d * 136 + sc2];
            }
        }
        return;
    }
    #pragma unroll
    for (int m = 0; m < 8; m++) {
        #pragma unroll
        for (int n = 0; n < 4; n++) {
            #pragma unroll
            for (int r = 0; r < 4; r++) {
                const size_t gr = (size_t)(row0 + wr * 128 + m * 16 + rb + r);
                const int gc = bcol + wc * 64 + n * 16 + lr;
                float x = acc[m][n][r];
                if (MODE == 0) {
                    if (!second) {
                        C1[gr * D_ + gc] = f2bf(featmap(x));
                    } else {
                        const int gc2 = gc - D_;
                        float t = x + bias[gc2];
                        C2[gr * D_ + gc2] = f2bf(1.f / (1.f + __expf(-t)));
                    }
                } else {
                    Cf[gr * D_ + gc] = x;
                }
            }
        }
    }
#undef STA
#undef STB
#undef RD_As
#undef RD_Bs
#undef MFMA_G
#undef PRIO1
#undef PRIO0
#undef BAR
#undef LG0
#undef VM4
#undef VM0
}

// kv_summary partials: per (s-chunk cx, bh): part[cx][bh][d][e] = sum_s k[s,d]*v[s,e]
__global__ __launch_bounds__(256) void kvsum_part(
    const unsigned short* __restrict__ kT, const unsigned short* __restrict__ vT,
    float* __restrict__ part, float* __restrict__ ksum_part)
{
    __shared__ unsigned short kA[HD_ * LDSS];
    __shared__ unsigned short vB[HD_ * LDSS];
    __shared__ float red[HD_ * 8];
    const int tid = threadIdx.x;
    const int cx = blockIdx.x, bh = blockIdx.y;
    const int lane = tid & 63, w = tid >> 6;
    const int wm = (w >> 1) * 64, wn = (w & 1) * 64;
    const int lr = lane & 15, lk = (lane >> 4) * 8;
    const unsigned short* kb = kT + (size_t)bh * HD_ * S_;
    const unsigned short* vb = vT + (size_t)bh * HD_ * S_;
    f32x4 acc[4][4] = {};
    float ksl[4] = {0.f, 0.f, 0.f, 0.f};
    const int chunk = S_ / 8;
    const int s_begin = cx * chunk;
    for (int s0 = s_begin; s0 < s_begin + chunk; s0 += 64) {
        #pragma unroll
        for (int i = 0; i < 4; i++) {
            int idx = tid + i * 256;
            int d = idx >> 3, sc = (idx & 7) * 8;
            u32x4 kk = *(const u32x4*)&kb[(size_t)d * S_ + s0 + sc];
            *(u32x4*)&kA[d * LDSS + sc] = kk;
            unsigned short t8[8];
            *(u32x4*)t8 = kk;
            float ss = 0.f;
            #pragma unroll
            for (int j = 0; j < 8; j++) ss += bf2f(t8[j]);
            ksl[i] += ss;
            *(u32x4*)&vB[d * LDSS + sc] = *(const u32x4*)&vb[(size_t)d * S_ + s0 + sc];
        }
        __syncthreads();
        #pragma unroll
        for (int ks = 0; ks < 64; ks += 32) {
            bf16x8 av[4], bv[4];
            #pragma unroll
            for (int mi = 0; mi < 4; mi++)
                av[mi] = *(const bf16x8*)&kA[(wm + mi * 16 + lr) * LDSS + ks + lk];
            #pragma unroll
            for (int ni = 0; ni < 4; ni++)
                bv[ni] = *(const bf16x8*)&vB[(wn + ni * 16 + lr) * LDSS + ks + lk];
            #pragma unroll
            for (int mi = 0; mi < 4; mi++)
                #pragma unroll
                for (int ni = 0; ni < 4; ni++)
                    acc[mi][ni] = __builtin_amdgcn_mfma_f32_16x16x32_bf16(
                        av[mi], bv[ni], acc[mi][ni], 0, 0, 0);
        }
        __syncthreads();
    }
    #pragma unroll
    for (int i = 0; i < 4; i++) red[((tid >> 3) + 32 * i) * 8 + (tid & 7)] = ksl[i];
    __syncthreads();
    if (tid < HD_) {
        float s = 0.f;
        #pragma unroll
        for (int j = 0; j < 8; j++) s += red[tid * 8 + j];
        ksum_part[(size_t)cx * (64 * HD_) + bh * HD_ + tid] = s;
    }
    const int rb = (lane >> 4) * 4;
    float* pp = part + ((size_t)cx * 64 + bh) * (HD_ * HD_);
    #pragma unroll
    for (int mi = 0; mi < 4; mi++)
        #pragma unroll
        for (int ni = 0; ni < 4; ni++)
            #pragma unroll
            for (int r = 0; r < 4; r++)
                pp[(wm + mi * 16 + rb + r) * HD_ + wn + ni * 16 + lr] = acc[mi][ni][r];
}

__global__ __launch_bounds__(256) void kvs_reduce(
    const float* __restrict__ part, unsigned short* __restrict__ kvsT,
    const float* __restrict__ ksum_part, float* __restrict__ ksum)
{
    const int idx = blockIdx.x * 256 + threadIdx.x;
    const int e = idx & 127, d2 = (idx >> 7) & 127, bh = idx >> 14;
    float s = 0.f;
    #pragma unroll
    for (int cx = 0; cx < 8; cx++)
        s += part[((size_t)cx * 64 + bh) * 16384 + d2 * 128 + e];
    kvsT[((size_t)bh * 128 + e) * 128 + d2] = f2bf(s);
    if (idx < 64 * 128) {
        float t = 0.f;
        #pragma unroll
        for (int cx = 0; cx < 8; cx++) t += ksum_part[cx * 8192 + idx];
        ksum[idx] = t;
    }
}

// attn = (q @ kvs) * z * gate -> y (bf16)
__global__ __launch_bounds__(256) void attn_kernel(
    const unsigned short* __restrict__ qf, const unsigned short* __restrict__ kvsT,
    const float* __restrict__ ksum, const unsigned short* __restrict__ gate,
    unsigned short* __restrict__ y)
{
    __shared__ unsigned short qs[128 * 136];
    __shared__ unsigned short bs[128 * LDSS];
    __shared__ float zl[128];
    const int tid = threadIdx.x;
    const int l0 = blockIdx.x * 128;
    const int h = blockIdx.y, b = blockIdx.z;
    const int bh = b * H_ + h;
    const int lane = tid & 63, w = tid >> 6;
    const int wm = (w >> 1) * 64, wn = (w & 1) * 64;
    const int lr = lane & 15, lk = (lane >> 4) * 8;
    const size_t qbase = (size_t)b * L_ * D_ + (size_t)h * HD_;
    #pragma unroll
    for (int i = 0; i < 8; i++) {
        int idx = tid + i * 256;
        int r = idx >> 4, c = (idx & 15) * 8;
        *(u32x4*)&qs[r * 136 + c] = *(const u32x4*)&qf[qbase + (size_t)(l0 + r) * D_ + c];
    }
    __syncthreads();
    if (tid < 128) {
        const float* kp = ksum + bh * HD_;
        float sden = 0.f;
        #pragma unroll 4
        for (int d2 = 0; d2 < HD_; d2++) sden += bf2f(qs[tid * 136 + d2]) * kp[d2];
        zl[tid] = 1.f / (sden + 1e-6f);
    }
    f32x4 acc[4][4] = {};
    for (int kc = 0; kc < 2; kc++) {
        #pragma unroll
        for (int i = 0; i < 4; i++) {
            int idx = tid + i * 256;
            int e = idx >> 3, dc = (idx & 7) * 8;
            *(u32x4*)&bs[e * LDSS + dc] =
                *(const u32x4*)&kvsT[((size_t)bh * 128 + e) * 128 + kc * 64 + dc];
        }
        __syncthreads();
        #pragma unroll
        for (int ks = 0; ks < 64; ks += 32) {
            bf16x8 av[4], bv[4];
            #pragma unroll
            for (int mi = 0; mi < 4; mi++)
                av[mi] = *(const bf16x8*)&qs[(wm + mi * 16 + lr) * 136 + kc * 64 + ks + lk];
            #pragma unroll
            for (int ni = 0; ni < 4; ni++)
                bv[ni] = *(const bf16x8*)&bs[(wn + ni * 16 + lr) * LDSS + ks + lk];
            #pragma unroll
            for (int mi = 0; mi < 4; mi++)
                #pragma unroll
                for (int ni = 0; ni < 4; ni++)
                    acc[mi][ni] = __builtin_amdgcn_mfma_f32_16x16x32_bf16(
                        av[mi], bv[ni], acc[mi][ni], 0, 0, 0);
        }
        __syncthreads();
    }
    const int rb = (lane >> 4) * 4;
    #pragma unroll
    for (int mi = 0; mi < 4; mi++) {
        #pragma unroll
        for (int ni = 0; ni < 4; ni++) {
            #pragma unroll
            for (int r = 0; r < 4; r++) {
                int ll = wm + mi * 16 + rb + r;
                int e = wn + ni * 16 + lr;
                float attn = acc[mi][ni][r] * zl[ll];
                float g = bf2f(gate[qbase + (size_t)(l0 + ll) * D_ + e]);
                y[qbase + (size_t)(l0 + ll) * D_ + e] = f2bf(attn * g);
            }
        }
    }
}

extern "C" void kernel_launch(void* const* d_in, const int* in_sizes, int n_in,
                              void* d_out, int out_size, void* d_ws, size_t ws_size,
                              hipStream_t stream)
{
    (void)in_sizes; (void)n_in; (void)out_size; (void)ws_size;
    const float* query = (const float*)d_in[0];
    const float* kv    = (const float*)d_in[1];
    const float* Wq    = (const float*)d_in[2];
    const float* Wg    = (const float*)d_in[3];
    const float* bg    = (const float*)d_in[4];
    const float* Wkv   = (const float*)d_in[5];
    const float* Wo    = (const float*)d_in[6];
    float* out = (float*)d_out;
    char* ws = (char*)d_ws;

    // workspace layout (bytes). Region R is time-shared (stream-ordered).
    unsigned short* q_feat = (unsigned short*)(ws);                 // 64 MiB
    unsigned short* gate   = (unsigned short*)(ws + 67108864);      // 64 MiB
    unsigned short* kTb    = (unsigned short*)(ws + 134217728);     // 64 MiB [bh][d][s]
    unsigned short* vTb    = (unsigned short*)(ws + 201326592);     // 64 MiB [bh][d][s]
    char* R = ws + 268435456;
    unsigned short* qbf    = (unsigned short*)(R);                  // 64 MiB (phase1)
    unsigned short* Wqg    = (unsigned short*)(R + 67108864);       // 16 MiB (phase1)
    unsigned short* kvbf   = (unsigned short*)(R);                  // 64 MiB (phase2)
    unsigned short* Wkvb   = (unsigned short*)(R + 67108864);       // 16 MiB (phase2)
    float* part            = (float*)(R);                           // 32 MiB (phase3)
    float* ksum_part       = (float*)(R + 33554432);                // 256 KiB
    float* ksum            = (float*)(R + 33816576);                // 32 KiB
    unsigned short* kvsT   = (unsigned short*)(R + 33849344);       // 2 MiB
    unsigned short* Wob    = (unsigned short*)(R + 83886080);       // 8 MiB
    unsigned short* ybuf   = kTb;   // kT dead after kvsum_part

    dim3 blk(256, 1, 1);
    dim3 blk512(512, 1, 1);
    // ---- phase 1: q path ----
    cvt_bf16<<<dim3(2048), blk, 0, stream>>>(query, qbf, 4194304);
    cvt_bf16<<<dim3(2048), blk, 0, stream>>>(Wq, Wqg, 524288);
    cvt_bf16<<<dim3(2048), blk, 0, stream>>>(Wg, Wqg + 4194304, 524288);
    cvt_bf16<<<dim3(2048), blk, 0, stream>>>(Wo, Wob, 524288);
    gemm256<0, 16><<<dim3(1024), blk512, 0, stream>>>(qbf, Wqg, q_feat, gate, nullptr, bg);
    // ---- phase 2: kv path ----
    cvt_bf16<<<dim3(2048), blk, 0, stream>>>(kv, kvbf, 4194304);
    cvt_bf16<<<dim3(2048), blk, 0, stream>>>(Wkv, Wkvb, 1048576);
    gemm256<1, 16><<<dim3(1024), blk512, 0, stream>>>(kvbf, Wkvb, kTb, vTb, nullptr, nullptr);
    // ---- phase 3: summary + attention ----
    kvsum_part<<<dim3(8, 64), blk, 0, stream>>>(kTb, vTb, part, ksum_part);
    kvs_reduce<<<dim3(4096), blk, 0, stream>>>(part, kvsT, ksum_part, ksum);
    attn_kernel<<<dim3(32, 16, 4), blk, 0, stream>>>(q_feat, kvsT, ksum, gate, ybuf);
    // ---- output projection ----
    gemm256<2, 8><<<dim3(512), blk512, 0, stream>>>(ybuf, Wob, nullptr, nullptr, out, nullptr);
}

// Round 9
// 961.654 us; speedup vs baseline: 1.2714x; 1.2714x over previous
//
#include <hip/hip_runtime.h>

typedef __attribute__((ext_vector_type(8))) short bf16x8;
typedef __attribute__((ext_vector_type(4))) float f32x4;
typedef __attribute__((ext_vector_type(4))) unsigned int u32x4;

constexpr int L_ = 4096, S_ = 4096, D_ = 2048, H_ = 16, HD_ = 128;
constexpr int LDSS = 72; // padded stride for the small kernels

__device__ __forceinline__ unsigned short f2bf(float f) {
    unsigned int u = __builtin_bit_cast(unsigned int, f);
    return (unsigned short)((u + 0x7fffu + ((u >> 16) & 1u)) >> 16);
}
__device__ __forceinline__ float bf2f(unsigned short h) {
    unsigned int u = ((unsigned int)h) << 16;
    return __builtin_bit_cast(float, u);
}
__device__ __forceinline__ unsigned long long pack4(float a, float b, float c, float d) {
    return (unsigned long long)f2bf(a) | ((unsigned long long)f2bf(b) << 16)
         | ((unsigned long long)f2bf(c) << 32) | ((unsigned long long)f2bf(d) << 48);
}
__device__ __forceinline__ float featmap(float x) {
    return x > 0.f ? x + 1.f : __expf(x);
}
__device__ __forceinline__ void gload16(const unsigned short* g, unsigned short* l) {
    __builtin_amdgcn_global_load_lds(
        (const __attribute__((address_space(1))) void*)g,
        (__attribute__((address_space(3))) void*)l, 16, 0, 0);
}

// fp32 -> bf16 bulk convert
__global__ __launch_bounds__(256) void cvt_bf16(
    const float* __restrict__ in, unsigned short* __restrict__ out, int n8)
{
    const int stride = gridDim.x * 256;
    for (int i = blockIdx.x * 256 + threadIdx.x; i < n8; i += stride) {
        const float4 a = ((const float4*)in)[2 * i];
        const float4 b = ((const float4*)in)[2 * i + 1];
        unsigned long long* o = (unsigned long long*)&out[(size_t)i * 8];
        o[0] = pack4(a.x, a.y, a.z, a.w);
        o[1] = pack4(b.x, b.y, b.z, b.w);
    }
}

// ===================== 256x256 8-phase GEMM (R5 skeleton, counted lgkm) =====================
// C = A @ B^T. BK=64, 2 K-tiles/iter (buf0/buf1). 8 waves (2wr x 4wc), per-wave C=128x64.
// LDS 128KiB double-buffered. Each phase: {ds_reads (consumed by THIS phase's MFMAs) ||
// 1 stage} -> BAR -> setprio(1) -> 16 MFMA -> setprio(0) -> BAR. NO asm lgkmcnt(0):
// the reads are plain C++ loads, so the compiler emits counted per-consumer lgkm waits
// -> later reads complete under the MFMA shadow instead of a full pre-MFMA drain.
// WAR guard: lgkm retires in order, so all of a phase's reads are retired before its
// last MFMA issues, hence before the barrier, hence before any re-staging next phase.
// vmcnt(6) at P4/P8 only (counted, never 0 in loop): retires exactly one K-tile.
// Block remap: XCD chunk (8bm x NBN) traversed in 2x2 sub-blocks for L2 locality.
template<int MODE, int NBN>
__global__ __launch_bounds__(512, 2) void gemm256(
    const unsigned short* __restrict__ A, const unsigned short* __restrict__ B,
    unsigned short* __restrict__ C1, unsigned short* __restrict__ C2,
    float* __restrict__ Cf, const float* __restrict__ bias)
{
    __shared__ alignas(16) unsigned short lds[65536];   // 128 KiB
    const int tid = threadIdx.x;
    const int lane = tid & 63, w = tid >> 6;
    const int wr = w >> 2, wc = w & 3;
    const int lr = lane & 15;
    const int lk8 = (lane >> 4) * 8;          // K-element offset within 32-group
    const int rsw = (lr & 7) << 3;            // read-side swizzle (shorts)
    const int lsub = lane >> 3;               // 0..7
    const int scol = ((lane & 7) ^ lsub) * 8; // pre-swizzled source col (elements)

    // XCD swizzle + 2x2 sub-block order within each XCD chunk.
    // chunk = 8 bm-rows x NBN bn-cols (nwg = 64*NBN, nwg/8/NBN == 8 for our grids).
    const int wg = blockIdx.x;
    const int xcd = wg & 7, u = wg >> 3;      // u in [0, nwg/8)
    const int s = u >> 2, q = u & 3;          // 2x2 sub-block id / quadrant
    const int sbm = s & 3, sbn = s >> 2;      // 4 x (NBN/2) sub-grid
    const int bm = xcd * 8 + sbm * 2 + (q & 1);
    const int bn = sbn * 2 + (q >> 1);
    const int row0 = bm * 256, bcol = bn * 256;

    const unsigned short* Ap = A + (size_t)row0 * D_;
    const unsigned short* Bp = B + (size_t)bcol * D_;
    const int rA = w * 8 + lsub;                              // A stage row (r=0)
    const int rB = ((w * 8 + lsub) >> 5) * 64 + ((w * 8 + lsub) & 31); // B stage row base

    f32x4 acc[8][4] = {};
    bf16x8 av[2][4], bv[2][4];

#define STA(BUF, HH, KT) do { \
    const unsigned short* g_ = Ap + (size_t)((HH) * 64 + rA) * D_ + (KT) * 64 + scol; \
    unsigned short* l_ = &lds[(BUF) * 16384 + (HH) * 8192 + w * 512]; \
    gload16(g_, l_); gload16(g_ + (size_t)128 * D_, l_ + 4096); } while (0)

#define STB(BUF, HH, KT) do { \
    const unsigned short* g_ = Bp + (size_t)(rB + (HH) * 32) * D_ + (KT) * 64 + scol; \
    unsigned short* l_ = &lds[32768 + (BUF) * 16384 + (HH) * 8192 + w * 512]; \
    gload16(g_, l_); gload16(g_ + (size_t)128 * D_, l_ + 4096); } while (0)

#define RD_A(MQ, BUF) \
    _Pragma("unroll") for (int mi = 0; mi < 4; mi++) \
    _Pragma("unroll") for (int ks = 0; ks < 2; ks++) \
        av[ks][mi] = *(const bf16x8*)&lds[(BUF) * 16384 + (MQ) * 8192 \
            + (mi * 16 + lr + wr * 64) * 64 + ((ks * 32 + lk8) ^ rsw)];

#define RD_B(NQ, BUF) \
    _Pragma("unroll") for (int j = 0; j < 2; j++) \
    _Pragma("unroll") for (int ks = 0; ks < 2; ks++) \
        bv[ks][(NQ) * 2 + j] = *(const bf16x8*)&lds[32768 + (BUF) * 16384 + (NQ) * 8192 \
            + (j * 16 + lr + wc * 32) * 64 + ((ks * 32 + lk8) ^ rsw)];

#define MFMA_Q(MQ, NQ) \
    __builtin_amdgcn_s_setprio(1); \
    _Pragma("unroll") for (int mi = 0; mi < 4; mi++) \
    _Pragma("unroll") for (int j = 0; j < 2; j++) \
    _Pragma("unroll") for (int ks = 0; ks < 2; ks++) \
        acc[(MQ) * 4 + mi][(NQ) * 2 + j] = __builtin_amdgcn_mfma_f32_16x16x32_bf16( \
            av[ks][mi], bv[ks][(NQ) * 2 + j], acc[(MQ) * 4 + mi][(NQ) * 2 + j], 0, 0, 0); \
    __builtin_amdgcn_s_setprio(0);

#define BAR __builtin_amdgcn_s_barrier()
#define VM6 asm volatile("s_waitcnt vmcnt(6)" ::: "memory")
#define VM0 asm volatile("s_waitcnt vmcnt(0)" ::: "memory")

    // ---- prologue: tile0 (A0,B0,B1,A1) + tile1 (A0,B0,B1) ----
    STA(0, 0, 0); STB(0, 0, 0); STB(0, 1, 0); STA(0, 1, 0);
    STA(1, 0, 1); STB(1, 0, 1); STB(1, 1, 1);
    VM6;            // tile0's 4 half-tiles arrived
    BAR;

    constexpr int NT = D_ / 64;       // 32 K-tiles
    for (int i = 0; i < NT / 2 - 1; i++) {
        const int T = 2 * i;
        // P1: read A0,B0(buf0); Q(0,0)
        RD_A(0, 0); RD_B(0, 0); STA(1, 1, T + 1);
        BAR; MFMA_Q(0, 0); BAR;
        // P2: read B1(buf0); Q(0,1)
        RD_B(1, 0); STA(0, 0, T + 2);
        BAR; MFMA_Q(0, 1); BAR;
        // P3: read A1(buf0); Q(1,0)
        RD_A(1, 0); STB(0, 0, T + 2);
        BAR; MFMA_Q(1, 0); BAR;
        // P4: no reads; Q(1,1); gate tile T+1
        STB(0, 1, T + 2);
        VM6; BAR; MFMA_Q(1, 1); BAR;
        // P5
        RD_A(0, 1); RD_B(0, 1); STA(0, 1, T + 2);
        BAR; MFMA_Q(0, 0); BAR;
        // P6
        RD_B(1, 1); STA(1, 0, T + 3);
        BAR; MFMA_Q(0, 1); BAR;
        // P7
        RD_A(1, 1); STB(1, 0, T + 3);
        BAR; MFMA_Q(1, 0); BAR;
        // P8: gate tile T+2
        STB(1, 1, T + 3);
        VM6; BAR; MFMA_Q(1, 1); BAR;
    }
    // ---- peeled final iteration (T = NT-2): only the A1(NT-1) stage remains ----
    {
        RD_A(0, 0); RD_B(0, 0); STA(1, 1, NT - 1);
        BAR; MFMA_Q(0, 0); BAR;
        RD_B(1, 0);
        BAR; MFMA_Q(0, 1); BAR;
        RD_A(1, 0);
        BAR; MFMA_Q(1, 0); BAR;
        VM0; BAR; MFMA_Q(1, 1); BAR;
        RD_A(0, 1); RD_B(0, 1);
        BAR; MFMA_Q(0, 0); BAR;
        RD_B(1, 1);
        BAR; MFMA_Q(0, 1); BAR;
        RD_A(1, 1);
        BAR; MFMA_Q(1, 0); BAR;
        BAR; MFMA_Q(1, 1); BAR;
    }

    // ================= epilogue =================
    const int rb = (lane >> 4) * 4;
    const bool second = bn >= (NBN / 2);
    if (MODE == 1) {
        // transpose each 128(s) x 128(d) quadrant via LDS, store [bh][d][s]
        unsigned short* TT = lds;             // 128*136 shorts
        const int b = row0 >> 12;
        #pragma unroll
        for (int qd = 0; qd < 4; qd++) {
            const int sq = qd >> 1, dh = qd & 1;
            __syncthreads();
            if (wr == sq && (wc >> 1) == dh) {
                #pragma unroll
                for (int m = 0; m < 8; m++) {
                    #pragma unroll
                    for (int n = 0; n < 4; n++) {
                        float x0 = acc[m][n][0], x1 = acc[m][n][1];
                        float x2 = acc[m][n][2], x3 = acc[m][n][3];
                        if (!second) {
                            x0 = featmap(x0); x1 = featmap(x1);
                            x2 = featmap(x2); x3 = featmap(x3);
                        }
                        const int dcol = (wc & 1) * 64 + n * 16 + lr;
                        *(unsigned long long*)&TT[dcol * 136 + m * 16 + rb]
                            = pack4(x0, x1, x2, x3);
                    }
                }
            }
            __syncthreads();
            const int h2 = (bn & 7) * 2 + dh;
            const int s0 = (row0 + sq * 128) & (S_ - 1);
            unsigned short* dst = (second ? C2 : C1) + (size_t)(b * H_ + h2) * HD_ * S_;
            #pragma unroll
            for (int it = 0; it < 4; it++) {
                const int idx = it * 512 + tid;
                const int d = idx >> 4, sc2 = (idx & 15) * 8;
                *(u32x4*)&dst[(size_t)d * S_ + s0 + sc2] = *(const u32x4*)&TT[d * 136 + sc2];
            }
        }
        return;
    }
    #pragma unroll
    for (int m = 0; m < 8; m++) {
        #pragma unroll
        for (int n = 0; n < 4; n++) {
            #pragma unroll
            for (int r = 0; r < 4; r++) {
                const size_t gr = (size_t)(row0 + wr * 128 + m * 16 + rb + r);
                const int gc = bcol + wc * 64 + n * 16 + lr;
                float x = acc[m][n][r];
                if (MODE == 0) {
                    if (!second) {
                        C1[gr * D_ + gc] = f2bf(featmap(x));
                    } else {
                        const int gc2 = gc - D_;
                        float t = x + bias[gc2];
                        C2[gr * D_ + gc2] = f2bf(1.f / (1.f + __expf(-t)));
                    }
                } else {
                    Cf[gr * D_ + gc] = x;
                }
            }
        }
    }
#undef STA
#undef STB
#undef RD_A
#undef RD_B
#undef MFMA_Q
#undef BAR
#undef VM6
#undef VM0
}

// kv_summary partials: per (s-chunk cx, bh): part[cx][bh][d][e] = sum_s k[s,d]*v[s,e]
__global__ __launch_bounds__(256) void kvsum_part(
    const unsigned short* __restrict__ kT, const unsigned short* __restrict__ vT,
    float* __restrict__ part, float* __restrict__ ksum_part)
{
    __shared__ unsigned short kA[HD_ * LDSS];
    __shared__ unsigned short vB[HD_ * LDSS];
    __shared__ float red[HD_ * 8];
    const int tid = threadIdx.x;
    const int cx = blockIdx.x, bh = blockIdx.y;
    const int lane = tid & 63, w = tid >> 6;
    const int wm = (w >> 1) * 64, wn = (w & 1) * 64;
    const int lr = lane & 15, lk = (lane >> 4) * 8;
    const unsigned short* kb = kT + (size_t)bh * HD_ * S_;
    const unsigned short* vb = vT + (size_t)bh * HD_ * S_;
    f32x4 acc[4][4] = {};
    float ksl[4] = {0.f, 0.f, 0.f, 0.f};
    const int chunk = S_ / 8;
    const int s_begin = cx * chunk;
    for (int s0 = s_begin; s0 < s_begin + chunk; s0 += 64) {
        #pragma unroll
        for (int i = 0; i < 4; i++) {
            int idx = tid + i * 256;
            int d = idx >> 3, sc = (idx & 7) * 8;
            u32x4 kk = *(const u32x4*)&kb[(size_t)d * S_ + s0 + sc];
            *(u32x4*)&kA[d * LDSS + sc] = kk;
            unsigned short t8[8];
            *(u32x4*)t8 = kk;
            float ss = 0.f;
            #pragma unroll
            for (int j = 0; j < 8; j++) ss += bf2f(t8[j]);
            ksl[i] += ss;
            *(u32x4*)&vB[d * LDSS + sc] = *(const u32x4*)&vb[(size_t)d * S_ + s0 + sc];
        }
        __syncthreads();
        #pragma unroll
        for (int ks = 0; ks < 64; ks += 32) {
            bf16x8 av[4], bv[4];
            #pragma unroll
            for (int mi = 0; mi < 4; mi++)
                av[mi] = *(const bf16x8*)&kA[(wm + mi * 16 + lr) * LDSS + ks + lk];
            #pragma unroll
            for (int ni = 0; ni < 4; ni++)
                bv[ni] = *(const bf16x8*)&vB[(wn + ni * 16 + lr) * LDSS + ks + lk];
            #pragma unroll
            for (int mi = 0; mi < 4; mi++)
                #pragma unroll
                for (int ni = 0; ni < 4; ni++)
                    acc[mi][ni] = __builtin_amdgcn_mfma_f32_16x16x32_bf16(
                        av[mi], bv[ni], acc[mi][ni], 0, 0, 0);
        }
        __syncthreads();
    }
    #pragma unroll
    for (int i = 0; i < 4; i++) red[((tid >> 3) + 32 * i) * 8 + (tid & 7)] = ksl[i];
    __syncthreads();
    if (tid < HD_) {
        float s = 0.f;
        #pragma unroll
        for (int j = 0; j < 8; j++) s += red[tid * 8 + j];
        ksum_part[(size_t)cx * (64 * HD_) + bh * HD_ + tid] = s;
    }
    const int rb = (lane >> 4) * 4;
    float* pp = part + ((size_t)cx * 64 + bh) * (HD_ * HD_);
    #pragma unroll
    for (int mi = 0; mi < 4; mi++)
        #pragma unroll
        for (int ni = 0; ni < 4; ni++)
            #pragma unroll
            for (int r = 0; r < 4; r++)
                pp[(wm + mi * 16 + rb + r) * HD_ + wn + ni * 16 + lr] = acc[mi][ni][r];
}

__global__ __launch_bounds__(256) void kvs_reduce(
    const float* __restrict__ part, unsigned short* __restrict__ kvsT,
    const float* __restrict__ ksum_part, float* __restrict__ ksum)
{
    const int idx = blockIdx.x * 256 + threadIdx.x;
    const int e = idx & 127, d2 = (idx >> 7) & 127, bh = idx >> 14;
    float s = 0.f;
    #pragma unroll
    for (int cx = 0; cx < 8; cx++)
        s += part[((size_t)cx * 64 + bh) * 16384 + d2 * 128 + e];
    kvsT[((size_t)bh * 128 + e) * 128 + d2] = f2bf(s);
    if (idx < 64 * 128) {
        float t = 0.f;
        #pragma unroll
        for (int cx = 0; cx < 8; cx++) t += ksum_part[cx * 8192 + idx];
        ksum[idx] = t;
    }
}

// attn = (q @ kvs) * z * gate -> y (bf16)
__global__ __launch_bounds__(256) void attn_kernel(
    const unsigned short* __restrict__ qf, const unsigned short* __restrict__ kvsT,
    const float* __restrict__ ksum, const unsigned short* __restrict__ gate,
    unsigned short* __restrict__ y)
{
    __shared__ unsigned short qs[128 * 136];
    __shared__ unsigned short bs[128 * LDSS];
    __shared__ float zl[128];
    const int tid = threadIdx.x;
    const int l0 = blockIdx.x * 128;
    const int h = blockIdx.y, b = blockIdx.z;
    const int bh = b * H_ + h;
    const int lane = tid & 63, w = tid >> 6;
    const int wm = (w >> 1) * 64, wn = (w & 1) * 64;
    const int lr = lane & 15, lk = (lane >> 4) * 8;
    const size_t qbase = (size_t)b * L_ * D_ + (size_t)h * HD_;
    #pragma unroll
    for (int i = 0; i < 8; i++) {
        int idx = tid + i * 256;
        int r = idx >> 4, c = (idx & 15) * 8;
        *(u32x4*)&qs[r * 136 + c] = *(const u32x4*)&qf[qbase + (size_t)(l0 + r) * D_ + c];
    }
    __syncthreads();
    if (tid < 128) {
        const float* kp = ksum + bh * HD_;
        float sden = 0.f;
        #pragma unroll 4
        for (int d2 = 0; d2 < HD_; d2++) sden += bf2f(qs[tid * 136 + d2]) * kp[d2];
        zl[tid] = 1.f / (sden + 1e-6f);
    }
    f32x4 acc[4][4] = {};
    for (int kc = 0; kc < 2; kc++) {
        #pragma unroll
        for (int i = 0; i < 4; i++) {
            int idx = tid + i * 256;
            int e = idx >> 3, dc = (idx & 7) * 8;
            *(u32x4*)&bs[e * LDSS + dc] =
                *(const u32x4*)&kvsT[((size_t)bh * 128 + e) * 128 + kc * 64 + dc];
        }
        __syncthreads();
        #pragma unroll
        for (int ks = 0; ks < 64; ks += 32) {
            bf16x8 av[4], bv[4];
            #pragma unroll
            for (int mi = 0; mi < 4; mi++)
                av[mi] = *(const bf16x8*)&qs[(wm + mi * 16 + lr) * 136 + kc * 64 + ks + lk];
            #pragma unroll
            for (int ni = 0; ni < 4; ni++)
                bv[ni] = *(const bf16x8*)&bs[(wn + ni * 16 + lr) * LDSS + ks + lk];
            #pragma unroll
            for (int mi = 0; mi < 4; mi++)
                #pragma unroll
                for (int ni = 0; ni < 4; ni++)
                    acc[mi][ni] = __builtin_amdgcn_mfma_f32_16x16x32_bf16(
                        av[mi], bv[ni], acc[mi][ni], 0, 0, 0);
        }
        __syncthreads();
    }
    const int rb = (lane >> 4) * 4;
    #pragma unroll
    for (int mi = 0; mi < 4; mi++) {
        #pragma unroll
        for (int ni = 0; ni < 4; ni++) {
            #pragma unroll
            for (int r = 0; r < 4; r++) {
                int ll = wm + mi * 16 + rb + r;
                int e = wn + ni * 16 + lr;
                float attn = acc[mi][ni][r] * zl[ll];
                float g = bf2f(gate[qbase + (size_t)(l0 + ll) * D_ + e]);
                y[qbase + (size_t)(l0 + ll) * D_ + e] = f2bf(attn * g);
            }
        }
    }
}

extern "C" void kernel_launch(void* const* d_in, const int* in_sizes, int n_in,
                              void* d_out, int out_size, void* d_ws, size_t ws_size,
                              hipStream_t stream)
{
    (void)in_sizes; (void)n_in; (void)out_size; (void)ws_size;
    const float* query = (const float*)d_in[0];
    const float* kv    = (const float*)d_in[1];
    const float* Wq    = (const float*)d_in[2];
    const float* Wg    = (const float*)d_in[3];
    const float* bg    = (const float*)d_in[4];
    const float* Wkv   = (const float*)d_in[5];
    const float* Wo    = (const float*)d_in[6];
    float* out = (float*)d_out;
    char* ws = (char*)d_ws;

    // workspace layout (bytes). Region R is time-shared (stream-ordered).
    unsigned short* q_feat = (unsigned short*)(ws);                 // 64 MiB
    unsigned short* gate   = (unsigned short*)(ws + 67108864);      // 64 MiB
    unsigned short* kTb    = (unsigned short*)(ws + 134217728);     // 64 MiB [bh][d][s]
    unsigned short* vTb    = (unsigned short*)(ws + 201326592);     // 64 MiB [bh][d][s]
    char* R = ws + 268435456;
    unsigned short* qbf    = (unsigned short*)(R);                  // 64 MiB (phase1)
    unsigned short* Wqg    = (unsigned short*)(R + 67108864);       // 16 MiB (phase1)
    unsigned short* kvbf   = (unsigned short*)(R);                  // 64 MiB (phase2)
    unsigned short* Wkvb   = (unsigned short*)(R + 67108864);       // 16 MiB (phase2)
    float* part            = (float*)(R);                           // 32 MiB (phase3)
    float* ksum_part       = (float*)(R + 33554432);                // 256 KiB
    float* ksum            = (float*)(R + 33816576);                // 32 KiB
    unsigned short* kvsT   = (unsigned short*)(R + 33849344);       // 2 MiB
    unsigned short* Wob    = (unsigned short*)(R + 83886080);       // 8 MiB
    unsigned short* ybuf   = kTb;   // kT dead after kvsum_part

    dim3 blk(256, 1, 1);
    dim3 blk512(512, 1, 1);
    // ---- phase 1: q path ----
    cvt_bf16<<<dim3(2048), blk, 0, stream>>>(query, qbf, 4194304);
    cvt_bf16<<<dim3(2048), blk, 0, stream>>>(Wq, Wqg, 524288);
    cvt_bf16<<<dim3(2048), blk, 0, stream>>>(Wg, Wqg + 4194304, 524288);
    cvt_bf16<<<dim3(2048), blk, 0, stream>>>(Wo, Wob, 524288);
    gemm256<0, 16><<<dim3(1024), blk512, 0, stream>>>(qbf, Wqg, q_feat, gate, nullptr, bg);
    // ---- phase 2: kv path ----
    cvt_bf16<<<dim3(2048), blk, 0, stream>>>(kv, kvbf, 4194304);
    cvt_bf16<<<dim3(2048), blk, 0, stream>>>(Wkv, Wkvb, 1048576);
    gemm256<1, 16><<<dim3(1024), blk512, 0, stream>>>(kvbf, Wkvb, kTb, vTb, nullptr, nullptr);
    // ---- phase 3: summary + attention ----
    kvsum_part<<<dim3(8, 64), blk, 0, stream>>>(kTb, vTb, part, ksum_part);
    kvs_reduce<<<dim3(4096), blk, 0, stream>>>(part, kvsT, ksum_part, ksum);
    attn_kernel<<<dim3(32, 16, 4), blk, 0, stream>>>(q_feat, kvsT, ksum, gate, ybuf);
    // ---- output projection ----
    gemm256<2, 8><<<dim3(512), blk512, 0, stream>>>(ybuf, Wob, nullptr, nullptr, out, nullptr);
}

// Round 10
// 950.950 us; speedup vs baseline: 1.2857x; 1.0113x over previous
//
#include <hip/hip_runtime.h>

typedef __attribute__((ext_vector_type(8))) short bf16x8;
typedef __attribute__((ext_vector_type(4))) float f32x4;
typedef __attribute__((ext_vector_type(4))) unsigned int u32x4;

constexpr int L_ = 4096, S_ = 4096, D_ = 2048, H_ = 16, HD_ = 128;
constexpr int LDSS = 72; // padded stride for the small kernels

__device__ __forceinline__ unsigned short f2bf(float f) {
    unsigned int u = __builtin_bit_cast(unsigned int, f);
    return (unsigned short)((u + 0x7fffu + ((u >> 16) & 1u)) >> 16);
}
__device__ __forceinline__ float bf2f(unsigned short h) {
    unsigned int u = ((unsigned int)h) << 16;
    return __builtin_bit_cast(float, u);
}
__device__ __forceinline__ unsigned long long pack4(float a, float b, float c, float d) {
    return (unsigned long long)f2bf(a) | ((unsigned long long)f2bf(b) << 16)
         | ((unsigned long long)f2bf(c) << 32) | ((unsigned long long)f2bf(d) << 48);
}
__device__ __forceinline__ float featmap(float x) {
    return x > 0.f ? x + 1.f : __expf(x);
}
__device__ __forceinline__ void gload16(const unsigned short* g, unsigned short* l) {
    __builtin_amdgcn_global_load_lds(
        (const __attribute__((address_space(1))) void*)g,
        (__attribute__((address_space(3))) void*)l, 16, 0, 0);
}

// fp32 -> bf16 bulk convert
__global__ __launch_bounds__(256) void cvt_bf16(
    const float* __restrict__ in, unsigned short* __restrict__ out, int n8)
{
    const int stride = gridDim.x * 256;
    for (int i = blockIdx.x * 256 + threadIdx.x; i < n8; i += stride) {
        const float4 a = ((const float4*)in)[2 * i];
        const float4 b = ((const float4*)in)[2 * i + 1];
        unsigned long long* o = (unsigned long long*)&out[(size_t)i * 8];
        o[0] = pack4(a.x, a.y, a.z, a.w);
        o[1] = pack4(b.x, b.y, b.z, b.w);
    }
}

// ============ 256x256 8-phase GEMM: B-prefetch into dead slots + 1 barrier/phase ============
// C = A @ B^T. BK=64, 2 K-tiles/iter (buf0/buf1). 8 waves (2wr x 4wc), per-wave C=128x64.
// Quadrant order per tile: Q00,Q01,Q11,Q10 (adjacent phases share one operand).
// bv01 = B0(tile) used in Q00/Q10; bv23 = B1(tile) used in Q01/Q11. Both halves of the
// NEXT tile's B are prefetched post-MFMA at P4/P8 (after the VM6 gate) into the then-dead
// bv slots -> consumed across the barrier via compiler-counted lgkm waits. Only the two
// A-half reads (8 ds_read_b128 each, P1/P3) remain exposed. ONE s_barrier per phase:
// each phase's reads are drained by its own MFMA cluster (counted lgkm, in-order) before
// the barrier, and same-phase stage regions are disjoint from read regions (ledger below).
// sched_barrier(0) after each MFMA cluster pins it before the barrier (rule-18 insurance).
// vmcnt(6) at P4/P8 only. Ledger: P4-VM6 retires {f,g,h,a} = tile T+1; P8-VM6 retires
// {b,c,d,e} = tile T+2; 6 loads stay in flight across each gate.
template<int MODE, int NBN>
__global__ __launch_bounds__(512, 2) void gemm256(
    const unsigned short* __restrict__ A, const unsigned short* __restrict__ B,
    unsigned short* __restrict__ C1, unsigned short* __restrict__ C2,
    float* __restrict__ Cf, const float* __restrict__ bias)
{
    __shared__ alignas(16) unsigned short lds[65536];   // 128 KiB
    const int tid = threadIdx.x;
    const int lane = tid & 63, w = tid >> 6;
    const int wr = w >> 2, wc = w & 3;
    const int lr = lane & 15;
    const int lk8 = (lane >> 4) * 8;          // K-element offset within 32-group
    const int rsw = (lr & 7) << 3;            // read-side swizzle (shorts)
    const int lsub = lane >> 3;               // 0..7
    const int scol = ((lane & 7) ^ lsub) * 8; // pre-swizzled source col (elements)

    // XCD swizzle + 2x2 sub-block order within each XCD chunk (L2 locality, R9).
    const int wg = blockIdx.x;
    const int xcd = wg & 7, u = wg >> 3;
    const int s = u >> 2, q = u & 3;
    const int sbm = s & 3, sbn = s >> 2;
    const int bm = xcd * 8 + sbm * 2 + (q & 1);
    const int bn = sbn * 2 + (q >> 1);
    const int row0 = bm * 256, bcol = bn * 256;

    const unsigned short* Ap = A + (size_t)row0 * D_;
    const unsigned short* Bp = B + (size_t)bcol * D_;
    const int rA = w * 8 + lsub;                              // A stage row (r=0)
    const int rB = ((w * 8 + lsub) >> 5) * 64 + ((w * 8 + lsub) & 31); // B stage row base

    f32x4 acc[8][4] = {};
    bf16x8 av[2][4], bv[2][4];

#define STA(BUF, HH, KT) do { \
    const unsigned short* g_ = Ap + (size_t)((HH) * 64 + rA) * D_ + (KT) * 64 + scol; \
    unsigned short* l_ = &lds[(BUF) * 16384 + (HH) * 8192 + w * 512]; \
    gload16(g_, l_); gload16(g_ + (size_t)128 * D_, l_ + 4096); } while (0)

#define STB(BUF, HH, KT) do { \
    const unsigned short* g_ = Bp + (size_t)(rB + (HH) * 32) * D_ + (KT) * 64 + scol; \
    unsigned short* l_ = &lds[32768 + (BUF) * 16384 + (HH) * 8192 + w * 512]; \
    gload16(g_, l_); gload16(g_ + (size_t)128 * D_, l_ + 4096); } while (0)

#define RD_A(MQ, BUF) \
    _Pragma("unroll") for (int mi = 0; mi < 4; mi++) \
    _Pragma("unroll") for (int ks = 0; ks < 2; ks++) \
        av[ks][mi] = *(const bf16x8*)&lds[(BUF) * 16384 + (MQ) * 8192 \
            + (mi * 16 + lr + wr * 64) * 64 + ((ks * 32 + lk8) ^ rsw)];

#define RD_B(NQ, BUF) \
    _Pragma("unroll") for (int j = 0; j < 2; j++) \
    _Pragma("unroll") for (int ks = 0; ks < 2; ks++) \
        bv[ks][(NQ) * 2 + j] = *(const bf16x8*)&lds[32768 + (BUF) * 16384 + (NQ) * 8192 \
            + (j * 16 + lr + wc * 32) * 64 + ((ks * 32 + lk8) ^ rsw)];

#define MFMA_Q(MQ, NQ) \
    __builtin_amdgcn_s_setprio(1); \
    _Pragma("unroll") for (int mi = 0; mi < 4; mi++) \
    _Pragma("unroll") for (int j = 0; j < 2; j++) \
    _Pragma("unroll") for (int ks = 0; ks < 2; ks++) \
        acc[(MQ) * 4 + mi][(NQ) * 2 + j] = __builtin_amdgcn_mfma_f32_16x16x32_bf16( \
            av[ks][mi], bv[ks][(NQ) * 2 + j], acc[(MQ) * 4 + mi][(NQ) * 2 + j], 0, 0, 0); \
    __builtin_amdgcn_s_setprio(0);

#define SB0 __builtin_amdgcn_sched_barrier(0)
#define BAR __builtin_amdgcn_s_barrier()
#define VM6 asm volatile("s_waitcnt vmcnt(6)" ::: "memory")
#define VM0 asm volatile("s_waitcnt vmcnt(0)" ::: "memory")

    // ---- prologue: tile0 (8 loads) + tile1 partial {A0,B0,B1} (6 loads) ----
    STA(0, 0, 0); STB(0, 0, 0); STB(0, 1, 0); STA(0, 1, 0);
    STA(1, 0, 1); STB(1, 0, 1); STB(1, 1, 1);
    VM6;            // retires tile0's 8 loads
    BAR;
    RD_B(0, 0); RD_B(1, 0);     // bv01,bv23 <- B0,B1 (tile0)

    constexpr int NT = D_ / 64;       // 32 K-tiles
    for (int i = 0; i < NT / 2 - 1; i++) {
        const int T = 2 * i;
        // P1: Q00 on [av<-A0(buf0), bv01]; stage a
        RD_A(0, 0); STA(1, 1, T + 1);
        MFMA_Q(0, 0); SB0; BAR;
        // P2: Q01 on [av, bv23] (no reads); stage b
        STA(0, 0, T + 2);
        MFMA_Q(0, 1); SB0; BAR;
        // P3: Q11 on [av<-A1(buf0), bv23]; stage c
        RD_A(1, 0); STB(0, 0, T + 2);
        MFMA_Q(1, 1); SB0; BAR;
        // P4: Q10 on [av, bv01]; stage d; gate tile T+1; prefetch B(buf1)
        STB(0, 1, T + 2);
        MFMA_Q(1, 0);
        VM6; RD_B(0, 1); RD_B(1, 1);
        SB0; BAR;
        // P5: Q00 on [av<-A0(buf1), bv01]; stage e
        RD_A(0, 1); STA(0, 1, T + 2);
        MFMA_Q(0, 0); SB0; BAR;
        // P6: Q01 (no reads); stage f
        STA(1, 0, T + 3);
        MFMA_Q(0, 1); SB0; BAR;
        // P7: Q11 on [av<-A1(buf1), bv23]; stage g
        RD_A(1, 1); STB(1, 0, T + 3);
        MFMA_Q(1, 1); SB0; BAR;
        // P8: Q10; stage h; gate tile T+2; prefetch B(buf0)
        STB(1, 1, T + 3);
        MFMA_Q(1, 0);
        VM6; RD_B(0, 0); RD_B(1, 0);
        SB0; BAR;
    }
    // ---- peeled final body (tiles NT-2 buf0, NT-1 buf1): only stage a remains ----
    {
        RD_A(0, 0); STA(1, 1, NT - 1);
        MFMA_Q(0, 0); SB0; BAR;
        MFMA_Q(0, 1); SB0; BAR;
        RD_A(1, 0);
        MFMA_Q(1, 1); SB0; BAR;
        MFMA_Q(1, 0);
        VM0; RD_B(0, 1); RD_B(1, 1);    // drain f,g,h,a then read B(buf1)
        SB0; BAR;
        RD_A(0, 1);
        MFMA_Q(0, 0); SB0; BAR;
        MFMA_Q(0, 1); SB0; BAR;
        RD_A(1, 1);
        MFMA_Q(1, 1); SB0; BAR;
        MFMA_Q(1, 0); SB0; BAR;
    }

    // ================= epilogue =================
    const int rb = (lane >> 4) * 4;
    const bool second = bn >= (NBN / 2);
    if (MODE == 1) {
        // transpose each 128(s) x 128(d) quadrant via LDS, store [bh][d][s]
        unsigned short* TT = lds;             // 128*136 shorts
        const int b = row0 >> 12;
        #pragma unroll
        for (int qd = 0; qd < 4; qd++) {
            const int sq = qd >> 1, dh = qd & 1;
            __syncthreads();
            if (wr == sq && (wc >> 1) == dh) {
                #pragma unroll
                for (int m = 0; m < 8; m++) {
                    #pragma unroll
                    for (int n = 0; n < 4; n++) {
                        float x0 = acc[m][n][0], x1 = acc[m][n][1];
                        float x2 = acc[m][n][2], x3 = acc[m][n][3];
                        if (!second) {
                            x0 = featmap(x0); x1 = featmap(x1);
                            x2 = featmap(x2); x3 = featmap(x3);
                        }
                        const int dcol = (wc & 1) * 64 + n * 16 + lr;
                        *(unsigned long long*)&TT[dcol * 136 + m * 16 + rb]
                            = pack4(x0, x1, x2, x3);
                    }
                }
            }
            __syncthreads();
            const int h2 = (bn & 7) * 2 + dh;
            const int s0 = (row0 + sq * 128) & (S_ - 1);
            unsigned short* dst = (second ? C2 : C1) + (size_t)(b * H_ + h2) * HD_ * S_;
            #pragma unroll
            for (int it = 0; it < 4; it++) {
                const int idx = it * 512 + tid;
                const int d = idx >> 4, sc2 = (idx & 15) * 8;
                *(u32x4*)&dst[(size_t)d * S_ + s0 + sc2] = *(const u32x4*)&TT[d * 136 + sc2];
            }
        }
        return;
    }
    #pragma unroll
    for (int m = 0; m < 8; m++) {
        #pragma unroll
        for (int n = 0; n < 4; n++) {
            #pragma unroll
            for (int r = 0; r < 4; r++) {
                const size_t gr = (size_t)(row0 + wr * 128 + m * 16 + rb + r);
                const int gc = bcol + wc * 64 + n * 16 + lr;
                float x = acc[m][n][r];
                if (MODE == 0) {
                    if (!second) {
                        C1[gr * D_ + gc] = f2bf(featmap(x));
                    } else {
                        const int gc2 = gc - D_;
                        float t = x + bias[gc2];
                        C2[gr * D_ + gc2] = f2bf(1.f / (1.f + __expf(-t)));
                    }
                } else {
                    Cf[gr * D_ + gc] = x;
                }
            }
        }
    }
#undef STA
#undef STB
#undef RD_A
#undef RD_B
#undef MFMA_Q
#undef SB0
#undef BAR
#undef VM6
#undef VM0
}

// kv_summary partials: per (s-chunk cx, bh): part[cx][bh][d][e] = sum_s k[s,d]*v[s,e]
__global__ __launch_bounds__(256) void kvsum_part(
    const unsigned short* __restrict__ kT, const unsigned short* __restrict__ vT,
    float* __restrict__ part, float* __restrict__ ksum_part)
{
    __shared__ unsigned short kA[HD_ * LDSS];
    __shared__ unsigned short vB[HD_ * LDSS];
    __shared__ float red[HD_ * 8];
    const int tid = threadIdx.x;
    const int cx = blockIdx.x, bh = blockIdx.y;
    const int lane = tid & 63, w = tid >> 6;
    const int wm = (w >> 1) * 64, wn = (w & 1) * 64;
    const int lr = lane & 15, lk = (lane >> 4) * 8;
    const unsigned short* kb = kT + (size_t)bh * HD_ * S_;
    const unsigned short* vb = vT + (size_t)bh * HD_ * S_;
    f32x4 acc[4][4] = {};
    float ksl[4] = {0.f, 0.f, 0.f, 0.f};
    const int chunk = S_ / 8;
    const int s_begin = cx * chunk;
    for (int s0 = s_begin; s0 < s_begin + chunk; s0 += 64) {
        #pragma unroll
        for (int i = 0; i < 4; i++) {
            int idx = tid + i * 256;
            int d = idx >> 3, sc = (idx & 7) * 8;
            u32x4 kk = *(const u32x4*)&kb[(size_t)d * S_ + s0 + sc];
            *(u32x4*)&kA[d * LDSS + sc] = kk;
            unsigned short t8[8];
            *(u32x4*)t8 = kk;
            float ss = 0.f;
            #pragma unroll
            for (int j = 0; j < 8; j++) ss += bf2f(t8[j]);
            ksl[i] += ss;
            *(u32x4*)&vB[d * LDSS + sc] = *(const u32x4*)&vb[(size_t)d * S_ + s0 + sc];
        }
        __syncthreads();
        #pragma unroll
        for (int ks = 0; ks < 64; ks += 32) {
            bf16x8 av[4], bv[4];
            #pragma unroll
            for (int mi = 0; mi < 4; mi++)
                av[mi] = *(const bf16x8*)&kA[(wm + mi * 16 + lr) * LDSS + ks + lk];
            #pragma unroll
            for (int ni = 0; ni < 4; ni++)
                bv[ni] = *(const bf16x8*)&vB[(wn + ni * 16 + lr) * LDSS + ks + lk];
            #pragma unroll
            for (int mi = 0; mi < 4; mi++)
                #pragma unroll
                for (int ni = 0; ni < 4; ni++)
                    acc[mi][ni] = __builtin_amdgcn_mfma_f32_16x16x32_bf16(
                        av[mi], bv[ni], acc[mi][ni], 0, 0, 0);
        }
        __syncthreads();
    }
    #pragma unroll
    for (int i = 0; i < 4; i++) red[((tid >> 3) + 32 * i) * 8 + (tid & 7)] = ksl[i];
    __syncthreads();
    if (tid < HD_) {
        float s = 0.f;
        #pragma unroll
        for (int j = 0; j < 8; j++) s += red[tid * 8 + j];
        ksum_part[(size_t)cx * (64 * HD_) + bh * HD_ + tid] = s;
    }
    const int rb = (lane >> 4) * 4;
    float* pp = part + ((size_t)cx * 64 + bh) * (HD_ * HD_);
    #pragma unroll
    for (int mi = 0; mi < 4; mi++)
        #pragma unroll
        for (int ni = 0; ni < 4; ni++)
            #pragma unroll
            for (int r = 0; r < 4; r++)
                pp[(wm + mi * 16 + rb + r) * HD_ + wn + ni * 16 + lr] = acc[mi][ni][r];
}

__global__ __launch_bounds__(256) void kvs_reduce(
    const float* __restrict__ part, unsigned short* __restrict__ kvsT,
    const float* __restrict__ ksum_part, float* __restrict__ ksum)
{
    const int idx = blockIdx.x * 256 + threadIdx.x;
    const int e = idx & 127, d2 = (idx >> 7) & 127, bh = idx >> 14;
    float s = 0.f;
    #pragma unroll
    for (int cx = 0; cx < 8; cx++)
        s += part[((size_t)cx * 64 + bh) * 16384 + d2 * 128 + e];
    kvsT[((size_t)bh * 128 + e) * 128 + d2] = f2bf(s);
    if (idx < 64 * 128) {
        float t = 0.f;
        #pragma unroll
        for (int cx = 0; cx < 8; cx++) t += ksum_part[cx * 8192 + idx];
        ksum[idx] = t;
    }
}

// attn = (q @ kvs) * z * gate -> y (bf16)
__global__ __launch_bounds__(256) void attn_kernel(
    const unsigned short* __restrict__ qf, const unsigned short* __restrict__ kvsT,
    const float* __restrict__ ksum, const unsigned short* __restrict__ gate,
    unsigned short* __restrict__ y)
{
    __shared__ unsigned short qs[128 * 136];
    __shared__ unsigned short bs[128 * LDSS];
    __shared__ float zl[128];
    const int tid = threadIdx.x;
    const int l0 = blockIdx.x * 128;
    const int h = blockIdx.y, b = blockIdx.z;
    const int bh = b * H_ + h;
    const int lane = tid & 63, w = tid >> 6;
    const int wm = (w >> 1) * 64, wn = (w & 1) * 64;
    const int lr = lane & 15, lk = (lane >> 4) * 8;
    const size_t qbase = (size_t)b * L_ * D_ + (size_t)h * HD_;
    #pragma unroll
    for (int i = 0; i < 8; i++) {
        int idx = tid + i * 256;
        int r = idx >> 4, c = (idx & 15) * 8;
        *(u32x4*)&qs[r * 136 + c] = *(const u32x4*)&qf[qbase + (size_t)(l0 + r) * D_ + c];
    }
    __syncthreads();
    if (tid < 128) {
        const float* kp = ksum + bh * HD_;
        float sden = 0.f;
        #pragma unroll 4
        for (int d2 = 0; d2 < HD_; d2++) sden += bf2f(qs[tid * 136 + d2]) * kp[d2];
        zl[tid] = 1.f / (sden + 1e-6f);
    }
    f32x4 acc[4][4] = {};
    for (int kc = 0; kc < 2; kc++) {
        #pragma unroll
        for (int i = 0; i < 4; i++) {
            int idx = tid + i * 256;
            int e = idx >> 3, dc = (idx & 7) * 8;
            *(u32x4*)&bs[e * LDSS + dc] =
                *(const u32x4*)&kvsT[((size_t)bh * 128 + e) * 128 + kc * 64 + dc];
        }
        __syncthreads();
        #pragma unroll
        for (int ks = 0; ks < 64; ks += 32) {
            bf16x8 av[4], bv[4];
            #pragma unroll
            for (int mi = 0; mi < 4; mi++)
                av[mi] = *(const bf16x8*)&qs[(wm + mi * 16 + lr) * 136 + kc * 64 + ks + lk];
            #pragma unroll
            for (int ni = 0; ni < 4; ni++)
                bv[ni] = *(const bf16x8*)&bs[(wn + ni * 16 + lr) * LDSS + ks + lk];
            #pragma unroll
            for (int mi = 0; mi < 4; mi++)
                #pragma unroll
                for (int ni = 0; ni < 4; ni++)
                    acc[mi][ni] = __builtin_amdgcn_mfma_f32_16x16x32_bf16(
                        av[mi], bv[ni], acc[mi][ni], 0, 0, 0);
        }
        __syncthreads();
    }
    const int rb = (lane >> 4) * 4;
    #pragma unroll
    for (int mi = 0; mi < 4; mi++) {
        #pragma unroll
        for (int ni = 0; ni < 4; ni++) {
            #pragma unroll
            for (int r = 0; r < 4; r++) {
                int ll = wm + mi * 16 + rb + r;
                int e = wn + ni * 16 + lr;
                float attn = acc[mi][ni][r] * zl[ll];
                float g = bf2f(gate[qbase + (size_t)(l0 + ll) * D_ + e]);
                y[qbase + (size_t)(l0 + ll) * D_ + e] = f2bf(attn * g);
            }
        }
    }
}

extern "C" void kernel_launch(void* const* d_in, const int* in_sizes, int n_in,
                              void* d_out, int out_size, void* d_ws, size_t ws_size,
                              hipStream_t stream)
{
    (void)in_sizes; (void)n_in; (void)out_size; (void)ws_size;
    const float* query = (const float*)d_in[0];
    const float* kv    = (const float*)d_in[1];
    const float* Wq    = (const float*)d_in[2];
    const float* Wg    = (const float*)d_in[3];
    const float* bg    = (const float*)d_in[4];
    const float* Wkv   = (const float*)d_in[5];
    const float* Wo    = (const float*)d_in[6];
    float* out = (float*)d_out;
    char* ws = (char*)d_ws;

    // workspace layout (bytes). Region R is time-shared (stream-ordered).
    unsigned short* q_feat = (unsigned short*)(ws);                 // 64 MiB
    unsigned short* gate   = (unsigned short*)(ws + 67108864);      // 64 MiB
    unsigned short* kTb    = (unsigned short*)(ws + 134217728);     // 64 MiB [bh][d][s]
    unsigned short* vTb    = (unsigned short*)(ws + 201326592);     // 64 MiB [bh][d][s]
    char* R = ws + 268435456;
    unsigned short* qbf    = (unsigned short*)(R);                  // 64 MiB (phase1)
    unsigned short* Wqg    = (unsigned short*)(R + 67108864);       // 16 MiB (phase1)
    unsigned short* kvbf   = (unsigned short*)(R);                  // 64 MiB (phase2)
    unsigned short* Wkvb   = (unsigned short*)(R + 67108864);       // 16 MiB (phase2)
    float* part            = (float*)(R);                           // 32 MiB (phase3)
    float* ksum_part       = (float*)(R + 33554432);                // 256 KiB
    float* ksum            = (float*)(R + 33816576);                // 32 KiB
    unsigned short* kvsT   = (unsigned short*)(R + 33849344);       // 2 MiB
    unsigned short* Wob    = (unsigned short*)(R + 83886080);       // 8 MiB
    unsigned short* ybuf   = kTb;   // kT dead after kvsum_part

    dim3 blk(256, 1, 1);
    dim3 blk512(512, 1, 1);
    // ---- phase 1: q path ----
    cvt_bf16<<<dim3(2048), blk, 0, stream>>>(query, qbf, 4194304);
    cvt_bf16<<<dim3(2048), blk, 0, stream>>>(Wq, Wqg, 524288);
    cvt_bf16<<<dim3(2048), blk, 0, stream>>>(Wg, Wqg + 4194304, 524288);
    cvt_bf16<<<dim3(2048), blk, 0, stream>>>(Wo, Wob, 524288);
    gemm256<0, 16><<<dim3(1024), blk512, 0, stream>>>(qbf, Wqg, q_feat, gate, nullptr, bg);
    // ---- phase 2: kv path ----
    cvt_bf16<<<dim3(2048), blk, 0, stream>>>(kv, kvbf, 4194304);
    cvt_bf16<<<dim3(2048), blk, 0, stream>>>(Wkv, Wkvb, 1048576);
    gemm256<1, 16><<<dim3(1024), blk512, 0, stream>>>(kvbf, Wkvb, kTb, vTb, nullptr, nullptr);
    // ---- phase 3: summary + attention ----
    kvsum_part<<<dim3(8, 64), blk, 0, stream>>>(kTb, vTb, part, ksum_part);
    kvs_reduce<<<dim3(4096), blk, 0, stream>>>(part, kvsT, ksum_part, ksum);
    attn_kernel<<<dim3(32, 16, 4), blk, 0, stream>>>(q_feat, kvsT, ksum, gate, ybuf);
    // ---- output projection ----
    gemm256<2, 8><<<dim3(512), blk512, 0, stream>>>(ybuf, Wob, nullptr, nullptr, out, nullptr);
}

// Round 11
// 946.976 us; speedup vs baseline: 1.2911x; 1.0042x over previous
//
#include <hip/hip_runtime.h>

typedef __attribute__((ext_vector_type(8))) short bf16x8;
typedef __attribute__((ext_vector_type(4))) float f32x4;
typedef __attribute__((ext_vector_type(4))) unsigned int u32x4;

constexpr int L_ = 4096, S_ = 4096, D_ = 2048, H_ = 16, HD_ = 128;
constexpr int LDSS = 72; // padded stride for the small kernels

__device__ __forceinline__ unsigned short f2bf(float f) {
    unsigned int u = __builtin_bit_cast(unsigned int, f);
    return (unsigned short)((u + 0x7fffu + ((u >> 16) & 1u)) >> 16);
}
__device__ __forceinline__ float bf2f(unsigned short h) {
    unsigned int u = ((unsigned int)h) << 16;
    return __builtin_bit_cast(float, u);
}
__device__ __forceinline__ unsigned long long pack4(float a, float b, float c, float d) {
    return (unsigned long long)f2bf(a) | ((unsigned long long)f2bf(b) << 16)
         | ((unsigned long long)f2bf(c) << 32) | ((unsigned long long)f2bf(d) << 48);
}
__device__ __forceinline__ float featmap(float x) {
    return x > 0.f ? x + 1.f : __expf(x);
}
__device__ __forceinline__ void gload16(const unsigned short* g, unsigned short* l) {
    __builtin_amdgcn_global_load_lds(
        (const __attribute__((address_space(1))) void*)g,
        (__attribute__((address_space(3))) void*)l, 16, 0, 0);
}

// fp32 -> bf16 bulk convert
__global__ __launch_bounds__(256) void cvt_bf16(
    const float* __restrict__ in, unsigned short* __restrict__ out, int n8)
{
    const int stride = gridDim.x * 256;
    for (int i = blockIdx.x * 256 + threadIdx.x; i < n8; i += stride) {
        const float4 a = ((const float4*)in)[2 * i];
        const float4 b = ((const float4*)in)[2 * i + 1];
        unsigned long long* o = (unsigned long long*)&out[(size_t)i * 8];
        o[0] = pack4(a.x, a.y, a.z, a.w);
        o[1] = pack4(b.x, b.y, b.z, b.w);
    }
}

// ====== 256x256 8-phase GEMM: split-cluster interleave (R10 ledger unchanged) ======
// C = A @ B^T. BK=64, 2 K-tiles/iter (buf0/buf1). 8 waves (2wr x 4wc), per-wave C=128x64.
// Quadrants per tile: Q00,Q01,Q11,Q10. bv01=B0 used Q00/Q10; bv23=B1 used Q01/Q11.
// NEW vs R10: in read-phases the 8 av ds_reads are split 4+4 around the first 8-MFMA
// half-cluster; in P4/P8 the bv23-next reads (dead regs) interleave between MFMA halves.
// sched_group_barrier chains pin the interleave (prevent LLVM load-hoisting).
// vmcnt(6) at P4/P8 only: retires exactly one K-tile ({f,g,h,a} / {b,c,d,e}); B-next
// reads stay after the VM6 asm (memory-op ordering). One s_barrier per phase;
// sched_barrier(0) before it pins the phase body (rule-18 insurance).
template<int MODE, int NBN>
__global__ __launch_bounds__(512, 2) void gemm256(
    const unsigned short* __restrict__ A, const unsigned short* __restrict__ B,
    unsigned short* __restrict__ C1, unsigned short* __restrict__ C2,
    float* __restrict__ Cf, const float* __restrict__ bias)
{
    __shared__ alignas(16) unsigned short lds[65536];   // 128 KiB
    const int tid = threadIdx.x;
    const int lane = tid & 63, w = tid >> 6;
    const int wr = w >> 2, wc = w & 3;
    const int lr = lane & 15;
    const int lk8 = (lane >> 4) * 8;          // K-element offset within 32-group
    const int rsw = (lr & 7) << 3;            // read-side swizzle (shorts)
    const int lsub = lane >> 3;               // 0..7
    const int scol = ((lane & 7) ^ lsub) * 8; // pre-swizzled source col (elements)

    // XCD swizzle + 2x2 sub-block order within each XCD chunk (L2 locality).
    const int wg = blockIdx.x;
    const int xcd = wg & 7, u = wg >> 3;
    const int s = u >> 2, q = u & 3;
    const int sbm = s & 3, sbn = s >> 2;
    const int bm = xcd * 8 + sbm * 2 + (q & 1);
    const int bn = sbn * 2 + (q >> 1);
    const int row0 = bm * 256, bcol = bn * 256;

    const unsigned short* Ap = A + (size_t)row0 * D_;
    const unsigned short* Bp = B + (size_t)bcol * D_;
    const int rA = w * 8 + lsub;                              // A stage row (r=0)
    const int rB = ((w * 8 + lsub) >> 5) * 64 + ((w * 8 + lsub) & 31); // B stage row base

    f32x4 acc[8][4] = {};
    bf16x8 av[2][4], bv[2][4];

#define STA(BUF, HH, KT) do { \
    const unsigned short* g_ = Ap + (size_t)((HH) * 64 + rA) * D_ + (KT) * 64 + scol; \
    unsigned short* l_ = &lds[(BUF) * 16384 + (HH) * 8192 + w * 512]; \
    gload16(g_, l_); gload16(g_ + (size_t)128 * D_, l_ + 4096); } while (0)

#define STB(BUF, HH, KT) do { \
    const unsigned short* g_ = Bp + (size_t)(rB + (HH) * 32) * D_ + (KT) * 64 + scol; \
    unsigned short* l_ = &lds[32768 + (BUF) * 16384 + (HH) * 8192 + w * 512]; \
    gload16(g_, l_); gload16(g_ + (size_t)128 * D_, l_ + 4096); } while (0)

// 4 ds_read_b128: av[ks][2H..2H+1] <- A-half MQ of BUF
#define RD_A2(MQ, BUF, HH) \
    _Pragma("unroll") for (int mi = 2 * (HH); mi < 2 * (HH) + 2; mi++) \
    _Pragma("unroll") for (int ks = 0; ks < 2; ks++) \
        av[ks][mi] = *(const bf16x8*)&lds[(BUF) * 16384 + (MQ) * 8192 \
            + (mi * 16 + lr + wr * 64) * 64 + ((ks * 32 + lk8) ^ rsw)];

// 4 ds_read_b128: bv[ks][NQ*2+j] <- B-half NQ of BUF
#define RD_B(NQ, BUF) \
    _Pragma("unroll") for (int j = 0; j < 2; j++) \
    _Pragma("unroll") for (int ks = 0; ks < 2; ks++) \
        bv[ks][(NQ) * 2 + j] = *(const bf16x8*)&lds[32768 + (BUF) * 16384 + (NQ) * 8192 \
            + (j * 16 + lr + wc * 32) * 64 + ((ks * 32 + lk8) ^ rsw)];

// 8 MFMAs: mi in {2H, 2H+1}
#define MFMA_H(MQ, NQ, HH) \
    _Pragma("unroll") for (int mi = 2 * (HH); mi < 2 * (HH) + 2; mi++) \
    _Pragma("unroll") for (int j = 0; j < 2; j++) \
    _Pragma("unroll") for (int ks = 0; ks < 2; ks++) \
        acc[(MQ) * 4 + mi][(NQ) * 2 + j] = __builtin_amdgcn_mfma_f32_16x16x32_bf16( \
            av[ks][mi], bv[ks][(NQ) * 2 + j], acc[(MQ) * 4 + mi][(NQ) * 2 + j], 0, 0, 0);

#define MFMA_Q(MQ, NQ) \
    __builtin_amdgcn_s_setprio(1); \
    MFMA_H(MQ, NQ, 0) MFMA_H(MQ, NQ, 1) \
    __builtin_amdgcn_s_setprio(0);

#define SGB(m, n) __builtin_amdgcn_sched_group_barrier((m), (n), 0)
#define SB0 __builtin_amdgcn_sched_barrier(0)
#define BAR __builtin_amdgcn_s_barrier()
#define VM6 asm volatile("s_waitcnt vmcnt(6)" ::: "memory")
#define VM0 asm volatile("s_waitcnt vmcnt(0)" ::: "memory")

// read-phase: {4 ds_read | stage | 8 MFMA | 4 ds_read | 8 MFMA}
#define SGB_READPHASE \
    SGB(0x100, 4); SGB(0x70, 2); SGB(0x8, 8); SGB(0x100, 4); SGB(0x8, 8)
// gate-phase: {stage | 8 MFMA | 4 ds_read | 8 MFMA | 4 ds_read}
#define SGB_GATEPHASE \
    SGB(0x70, 2); SGB(0x8, 8); SGB(0x100, 4); SGB(0x8, 8); SGB(0x100, 4)

    // ---- prologue: tile0 (8 loads) + tile1 partial {A0,B0,B1} (6 loads) ----
    STA(0, 0, 0); STB(0, 0, 0); STB(0, 1, 0); STA(0, 1, 0);
    STA(1, 0, 1); STB(1, 0, 1); STB(1, 1, 1);
    VM6;            // retires tile0's 8 loads
    BAR;
    RD_B(0, 0); RD_B(1, 0);     // bv01,bv23 <- B0,B1 (tile0)

    constexpr int NT = D_ / 64;       // 32 K-tiles
    for (int i = 0; i < NT / 2 - 1; i++) {
        const int T = 2 * i;
        // P1: Q00 on [av<-A0(buf0), bv01]; stage a; split 4+4 reads around MFMA half
        RD_A2(0, 0, 0); STA(1, 1, T + 1);
        __builtin_amdgcn_s_setprio(1);
        MFMA_H(0, 0, 0)
        RD_A2(0, 0, 1);
        MFMA_H(0, 0, 1)
        __builtin_amdgcn_s_setprio(0);
        SGB_READPHASE; SB0; BAR;
        // P2: Q01 on [av, bv23] (no reads); stage b
        STA(0, 0, T + 2);
        MFMA_Q(0, 1); SB0; BAR;
        // P3: Q11 on [av<-A1(buf0), bv23]; stage c
        RD_A2(1, 0, 0); STB(0, 0, T + 2);
        __builtin_amdgcn_s_setprio(1);
        MFMA_H(1, 1, 0)
        RD_A2(1, 0, 1);
        MFMA_H(1, 1, 1)
        __builtin_amdgcn_s_setprio(0);
        SGB_READPHASE; SB0; BAR;
        // P4: Q10 on [av, bv01]; stage d; VM6; bv23-next interleaved, bv01-next after
        STB(0, 1, T + 2);
        VM6;
        __builtin_amdgcn_s_setprio(1);
        MFMA_H(1, 0, 0)
        RD_B(1, 1);                 // bv23 <- B1 (buf1, tile T+1) — dead since P3
        MFMA_H(1, 0, 1)
        __builtin_amdgcn_s_setprio(0);
        RD_B(0, 1);                 // bv01 <- B0 (buf1) — dead after this cluster
        SGB_GATEPHASE; SB0; BAR;
        // P5: Q00(buf1)
        RD_A2(0, 1, 0); STA(0, 1, T + 2);
        __builtin_amdgcn_s_setprio(1);
        MFMA_H(0, 0, 0)
        RD_A2(0, 1, 1);
        MFMA_H(0, 0, 1)
        __builtin_amdgcn_s_setprio(0);
        SGB_READPHASE; SB0; BAR;
        // P6: Q01 (no reads); stage f
        STA(1, 0, T + 3);
        MFMA_Q(0, 1); SB0; BAR;
        // P7: Q11 on [av<-A1(buf1), bv23]; stage g
        RD_A2(1, 1, 0); STB(1, 0, T + 3);
        __builtin_amdgcn_s_setprio(1);
        MFMA_H(1, 1, 0)
        RD_A2(1, 1, 1);
        MFMA_H(1, 1, 1)
        __builtin_amdgcn_s_setprio(0);
        SGB_READPHASE; SB0; BAR;
        // P8: Q10; stage h; VM6; bv(buf0, tile T+2) reads
        STB(1, 1, T + 3);
        VM6;
        __builtin_amdgcn_s_setprio(1);
        MFMA_H(1, 0, 0)
        RD_B(1, 0);                 // bv23 <- B1 (buf0, tile T+2)
        MFMA_H(1, 0, 1)
        __builtin_amdgcn_s_setprio(0);
        RD_B(0, 0);                 // bv01 <- B0 (buf0)
        SGB_GATEPHASE; SB0; BAR;
    }
    // ---- peeled final body (tiles NT-2 buf0, NT-1 buf1): only stage a remains ----
    {
        RD_A2(0, 0, 0); RD_A2(0, 0, 1); STA(1, 1, NT - 1);
        MFMA_Q(0, 0); SB0; BAR;
        MFMA_Q(0, 1); SB0; BAR;
        RD_A2(1, 0, 0); RD_A2(1, 0, 1);
        MFMA_Q(1, 1); SB0; BAR;
        MFMA_Q(1, 0);
        VM0; RD_B(0, 1); RD_B(1, 1);    // drain f,g,h,a then read B(buf1)
        SB0; BAR;
        RD_A2(0, 1, 0); RD_A2(0, 1, 1);
        MFMA_Q(0, 0); SB0; BAR;
        MFMA_Q(0, 1); SB0; BAR;
        RD_A2(1, 1, 0); RD_A2(1, 1, 1);
        MFMA_Q(1, 1); SB0; BAR;
        MFMA_Q(1, 0); SB0; BAR;
    }

    // ================= epilogue =================
    const int rb = (lane >> 4) * 4;
    const bool second = bn >= (NBN / 2);
    if (MODE == 1) {
        // transpose each 128(s) x 128(d) quadrant via LDS, store [bh][d][s]
        unsigned short* TT = lds;             // 128*136 shorts
        const int b = row0 >> 12;
        #pragma unroll
        for (int qd = 0; qd < 4; qd++) {
            const int sq = qd >> 1, dh = qd & 1;
            __syncthreads();
            if (wr == sq && (wc >> 1) == dh) {
                #pragma unroll
                for (int m = 0; m < 8; m++) {
                    #pragma unroll
                    for (int n = 0; n < 4; n++) {
                        float x0 = acc[m][n][0], x1 = acc[m][n][1];
                        float x2 = acc[m][n][2], x3 = acc[m][n][3];
                        if (!second) {
                            x0 = featmap(x0); x1 = featmap(x1);
                            x2 = featmap(x2); x3 = featmap(x3);
                        }
                        const int dcol = (wc & 1) * 64 + n * 16 + lr;
                        *(unsigned long long*)&TT[dcol * 136 + m * 16 + rb]
                            = pack4(x0, x1, x2, x3);
                    }
                }
            }
            __syncthreads();
            const int h2 = (bn & 7) * 2 + dh;
            const int s0 = (row0 + sq * 128) & (S_ - 1);
            unsigned short* dst = (second ? C2 : C1) + (size_t)(b * H_ + h2) * HD_ * S_;
            #pragma unroll
            for (int it = 0; it < 4; it++) {
                const int idx = it * 512 + tid;
                const int d = idx >> 4, sc2 = (idx & 15) * 8;
                *(u32x4*)&dst[(size_t)d * S_ + s0 + sc2] = *(const u32x4*)&TT[d * 136 + sc2];
            }
        }
        return;
    }
    #pragma unroll
    for (int m = 0; m < 8; m++) {
        #pragma unroll
        for (int n = 0; n < 4; n++) {
            #pragma unroll
            for (int r = 0; r < 4; r++) {
                const size_t gr = (size_t)(row0 + wr * 128 + m * 16 + rb + r);
                const int gc = bcol + wc * 64 + n * 16 + lr;
                float x = acc[m][n][r];
                if (MODE == 0) {
                    if (!second) {
                        C1[gr * D_ + gc] = f2bf(featmap(x));
                    } else {
                        const int gc2 = gc - D_;
                        float t = x + bias[gc2];
                        C2[gr * D_ + gc2] = f2bf(1.f / (1.f + __expf(-t)));
                    }
                } else {
                    Cf[gr * D_ + gc] = x;
                }
            }
        }
    }
#undef STA
#undef STB
#undef RD_A2
#undef RD_B
#undef MFMA_H
#undef MFMA_Q
#undef SGB
#undef SGB_READPHASE
#undef SGB_GATEPHASE
#undef SB0
#undef BAR
#undef VM6
#undef VM0
}

// kv_summary partials: per (s-chunk cx, bh): part[cx][bh][d][e] = sum_s k[s,d]*v[s,e]
__global__ __launch_bounds__(256) void kvsum_part(
    const unsigned short* __restrict__ kT, const unsigned short* __restrict__ vT,
    float* __restrict__ part, float* __restrict__ ksum_part)
{
    __shared__ unsigned short kA[HD_ * LDSS];
    __shared__ unsigned short vB[HD_ * LDSS];
    __shared__ float red[HD_ * 8];
    const int tid = threadIdx.x;
    const int cx = blockIdx.x, bh = blockIdx.y;
    const int lane = tid & 63, w = tid >> 6;
    const int wm = (w >> 1) * 64, wn = (w & 1) * 64;
    const int lr = lane & 15, lk = (lane >> 4) * 8;
    const unsigned short* kb = kT + (size_t)bh * HD_ * S_;
    const unsigned short* vb = vT + (size_t)bh * HD_ * S_;
    f32x4 acc[4][4] = {};
    float ksl[4] = {0.f, 0.f, 0.f, 0.f};
    const int chunk = S_ / 8;
    const int s_begin = cx * chunk;
    for (int s0 = s_begin; s0 < s_begin + chunk; s0 += 64) {
        #pragma unroll
        for (int i = 0; i < 4; i++) {
            int idx = tid + i * 256;
            int d = idx >> 3, sc = (idx & 7) * 8;
            u32x4 kk = *(const u32x4*)&kb[(size_t)d * S_ + s0 + sc];
            *(u32x4*)&kA[d * LDSS + sc] = kk;
            unsigned short t8[8];
            *(u32x4*)t8 = kk;
            float ss = 0.f;
            #pragma unroll
            for (int j = 0; j < 8; j++) ss += bf2f(t8[j]);
            ksl[i] += ss;
            *(u32x4*)&vB[d * LDSS + sc] = *(const u32x4*)&vb[(size_t)d * S_ + s0 + sc];
        }
        __syncthreads();
        #pragma unroll
        for (int ks = 0; ks < 64; ks += 32) {
            bf16x8 av[4], bv[4];
            #pragma unroll
            for (int mi = 0; mi < 4; mi++)
                av[mi] = *(const bf16x8*)&kA[(wm + mi * 16 + lr) * LDSS + ks + lk];
            #pragma unroll
            for (int ni = 0; ni < 4; ni++)
                bv[ni] = *(const bf16x8*)&vB[(wn + ni * 16 + lr) * LDSS + ks + lk];
            #pragma unroll
            for (int mi = 0; mi < 4; mi++)
                #pragma unroll
                for (int ni = 0; ni < 4; ni++)
                    acc[mi][ni] = __builtin_amdgcn_mfma_f32_16x16x32_bf16(
                        av[mi], bv[ni], acc[mi][ni], 0, 0, 0);
        }
        __syncthreads();
    }
    #pragma unroll
    for (int i = 0; i < 4; i++) red[((tid >> 3) + 32 * i) * 8 + (tid & 7)] = ksl[i];
    __syncthreads();
    if (tid < HD_) {
        float s = 0.f;
        #pragma unroll
        for (int j = 0; j < 8; j++) s += red[tid * 8 + j];
        ksum_part[(size_t)cx * (64 * HD_) + bh * HD_ + tid] = s;
    }
    const int rb = (lane >> 4) * 4;
    float* pp = part + ((size_t)cx * 64 + bh) * (HD_ * HD_);
    #pragma unroll
    for (int mi = 0; mi < 4; mi++)
        #pragma unroll
        for (int ni = 0; ni < 4; ni++)
            #pragma unroll
            for (int r = 0; r < 4; r++)
                pp[(wm + mi * 16 + rb + r) * HD_ + wn + ni * 16 + lr] = acc[mi][ni][r];
}

__global__ __launch_bounds__(256) void kvs_reduce(
    const float* __restrict__ part, unsigned short* __restrict__ kvsT,
    const float* __restrict__ ksum_part, float* __restrict__ ksum)
{
    const int idx = blockIdx.x * 256 + threadIdx.x;
    const int e = idx & 127, d2 = (idx >> 7) & 127, bh = idx >> 14;
    float s = 0.f;
    #pragma unroll
    for (int cx = 0; cx < 8; cx++)
        s += part[((size_t)cx * 64 + bh) * 16384 + d2 * 128 + e];
    kvsT[((size_t)bh * 128 + e) * 128 + d2] = f2bf(s);
    if (idx < 64 * 128) {
        float t = 0.f;
        #pragma unroll
        for (int cx = 0; cx < 8; cx++) t += ksum_part[cx * 8192 + idx];
        ksum[idx] = t;
    }
}

// attn = (q @ kvs) * z * gate -> y (bf16)
__global__ __launch_bounds__(256) void attn_kernel(
    const unsigned short* __restrict__ qf, const unsigned short* __restrict__ kvsT,
    const float* __restrict__ ksum, const unsigned short* __restrict__ gate,
    unsigned short* __restrict__ y)
{
    __shared__ unsigned short qs[128 * 136];
    __shared__ unsigned short bs[128 * LDSS];
    __shared__ float zl[128];
    const int tid = threadIdx.x;
    const int l0 = blockIdx.x * 128;
    const int h = blockIdx.y, b = blockIdx.z;
    const int bh = b * H_ + h;
    const int lane = tid & 63, w = tid >> 6;
    const int wm = (w >> 1) * 64, wn = (w & 1) * 64;
    const int lr = lane & 15, lk = (lane >> 4) * 8;
    const size_t qbase = (size_t)b * L_ * D_ + (size_t)h * HD_;
    #pragma unroll
    for (int i = 0; i < 8; i++) {
        int idx = tid + i * 256;
        int r = idx >> 4, c = (idx & 15) * 8;
        *(u32x4*)&qs[r * 136 + c] = *(const u32x4*)&qf[qbase + (size_t)(l0 + r) * D_ + c];
    }
    __syncthreads();
    if (tid < 128) {
        const float* kp = ksum + bh * HD_;
        float sden = 0.f;
        #pragma unroll 4
        for (int d2 = 0; d2 < HD_; d2++) sden += bf2f(qs[tid * 136 + d2]) * kp[d2];
        zl[tid] = 1.f / (sden + 1e-6f);
    }
    f32x4 acc[4][4] = {};
    for (int kc = 0; kc < 2; kc++) {
        #pragma unroll
        for (int i = 0; i < 4; i++) {
            int idx = tid + i * 256;
            int e = idx >> 3, dc = (idx & 7) * 8;
            *(u32x4*)&bs[e * LDSS + dc] =
                *(const u32x4*)&kvsT[((size_t)bh * 128 + e) * 128 + kc * 64 + dc];
        }
        __syncthreads();
        #pragma unroll
        for (int ks = 0; ks < 64; ks += 32) {
            bf16x8 av[4], bv[4];
            #pragma unroll
            for (int mi = 0; mi < 4; mi++)
                av[mi] = *(const bf16x8*)&qs[(wm + mi * 16 + lr) * 136 + kc * 64 + ks + lk];
            #pragma unroll
            for (int ni = 0; ni < 4; ni++)
                bv[ni] = *(const bf16x8*)&bs[(wn + ni * 16 + lr) * LDSS + ks + lk];
            #pragma unroll
            for (int mi = 0; mi < 4; mi++)
                #pragma unroll
                for (int ni = 0; ni < 4; ni++)
                    acc[mi][ni] = __builtin_amdgcn_mfma_f32_16x16x32_bf16(
                        av[mi], bv[ni], acc[mi][ni], 0, 0, 0);
        }
        __syncthreads();
    }
    const int rb = (lane >> 4) * 4;
    #pragma unroll
    for (int mi = 0; mi < 4; mi++) {
        #pragma unroll
        for (int ni = 0; ni < 4; ni++) {
            #pragma unroll
            for (int r = 0; r < 4; r++) {
                int ll = wm + mi * 16 + rb + r;
                int e = wn + ni * 16 + lr;
                float attn = acc[mi][ni][r] * zl[ll];
                float g = bf2f(gate[qbase + (size_t)(l0 + ll) * D_ + e]);
                y[qbase + (size_t)(l0 + ll) * D_ + e] = f2bf(attn * g);
            }
        }
    }
}

extern "C" void kernel_launch(void* const* d_in, const int* in_sizes, int n_in,
                              void* d_out, int out_size, void* d_ws, size_t ws_size,
                              hipStream_t stream)
{
    (void)in_sizes; (void)n_in; (void)out_size; (void)ws_size;
    const float* query = (const float*)d_in[0];
    const float* kv    = (const float*)d_in[1];
    const float* Wq    = (const float*)d_in[2];
    const float* Wg    = (const float*)d_in[3];
    const float* bg    = (const float*)d_in[4];
    const float* Wkv   = (const float*)d_in[5];
    const float* Wo    = (const float*)d_in[6];
    float* out = (float*)d_out;
    char* ws = (char*)d_ws;

    // workspace layout (bytes). Region R is time-shared (stream-ordered).
    unsigned short* q_feat = (unsigned short*)(ws);                 // 64 MiB
    unsigned short* gate   = (unsigned short*)(ws + 67108864);      // 64 MiB
    unsigned short* kTb    = (unsigned short*)(ws + 134217728);     // 64 MiB [bh][d][s]
    unsigned short* vTb    = (unsigned short*)(ws + 201326592);     // 64 MiB [bh][d][s]
    char* R = ws + 268435456;
    unsigned short* qbf    = (unsigned short*)(R);                  // 64 MiB (phase1)
    unsigned short* Wqg    = (unsigned short*)(R + 67108864);       // 16 MiB (phase1)
    unsigned short* kvbf   = (unsigned short*)(R);                  // 64 MiB (phase2)
    unsigned short* Wkvb   = (unsigned short*)(R + 67108864);       // 16 MiB (phase2)
    float* part            = (float*)(R);                           // 32 MiB (phase3)
    float* ksum_part       = (float*)(R + 33554432);                // 256 KiB
    float* ksum            = (float*)(R + 33816576);                // 32 KiB
    unsigned short* kvsT   = (unsigned short*)(R + 33849344);       // 2 MiB
    unsigned short* Wob    = (unsigned short*)(R + 83886080);       // 8 MiB
    unsigned short* ybuf   = kTb;   // kT dead after kvsum_part

    dim3 blk(256, 1, 1);
    dim3 blk512(512, 1, 1);
    // ---- phase 1: q path ----
    cvt_bf16<<<dim3(2048), blk, 0, stream>>>(query, qbf, 4194304);
    cvt_bf16<<<dim3(2048), blk, 0, stream>>>(Wq, Wqg, 524288);
    cvt_bf16<<<dim3(2048), blk, 0, stream>>>(Wg, Wqg + 4194304, 524288);
    cvt_bf16<<<dim3(2048), blk, 0, stream>>>(Wo, Wob, 524288);
    gemm256<0, 16><<<dim3(1024), blk512, 0, stream>>>(qbf, Wqg, q_feat, gate, nullptr, bg);
    // ---- phase 2: kv path ----
    cvt_bf16<<<dim3(2048), blk, 0, stream>>>(kv, kvbf, 4194304);
    cvt_bf16<<<dim3(2048), blk, 0, stream>>>(Wkv, Wkvb, 1048576);
    gemm256<1, 16><<<dim3(1024), blk512, 0, stream>>>(kvbf, Wkvb, kTb, vTb, nullptr, nullptr);
    // ---- phase 3: summary + attention ----
    kvsum_part<<<dim3(8, 64), blk, 0, stream>>>(kTb, vTb, part, ksum_part);
    kvs_reduce<<<dim3(4096), blk, 0, stream>>>(part, kvsT, ksum_part, ksum);
    attn_kernel<<<dim3(32, 16, 4), blk, 0, stream>>>(q_feat, kvsT, ksum, gate, ybuf);
    // ---- output projection ----
    gemm256<2, 8><<<dim3(512), blk512, 0, stream>>>(ybuf, Wob, nullptr, nullptr, out, nullptr);
}